// Round 5
// baseline (306.514 us; speedup 1.0000x reference)
//
#include <hip/hip_runtime.h>
#include <stdint.h>
#include <math.h>

typedef unsigned short u16;
typedef __attribute__((ext_vector_type(8))) short short8;   // 8 x bf16 (4 VGPRs)
typedef __attribute__((ext_vector_type(4))) float f32x4;    // MFMA acc
typedef __attribute__((ext_vector_type(4))) unsigned short u16x4;
typedef __attribute__((ext_vector_type(2))) unsigned int uint2v;

#define DEV static __device__ __forceinline__

DEV u16 f2bf(float f) {
    unsigned u = __builtin_bit_cast(unsigned, f);
    u = u + 0x7fffu + ((u >> 16) & 1u);   // RNE
    return (u16)(u >> 16);
}
DEV float bf2f(u16 s) { return __builtin_bit_cast(float, ((unsigned)s) << 16); }
// pack two f32 -> two bf16 in one dword (round-half-up; values are p=exp(s)>0)
DEV unsigned pk2(float a, float b) {
    unsigned ua = __builtin_bit_cast(unsigned, a) + 0x8000u;
    unsigned ub = __builtin_bit_cast(unsigned, b) + 0x8000u;
    return (ua >> 16) | (ub & 0xffff0000u);
}

// async 16B global -> LDS (m97 pattern)
DEV void gl_lds16(const u16* g, u16* l) {
#if __has_builtin(__builtin_amdgcn_global_load_lds)
    __builtin_amdgcn_global_load_lds((const __attribute__((address_space(1))) unsigned int*)g,
                                     (__attribute__((address_space(3))) unsigned int*)l, 16, 0, 0);
#else
    *(short8*)l = *(const short8*)g;
#endif
}

// B=2, N=2048, D=1024, H=16, HD=64

// ---------------- adaLN chain (fp32, silu fused into ada1) ----------------
__global__ __launch_bounds__(256) void k_ada1(const float* __restrict__ emb, const float* __restrict__ W,
                                              float* __restrict__ out) {
    int col = blockIdx.x * 64 + (threadIdx.x & 63);
    int b = blockIdx.y;
    int kseg = threadIdx.x >> 6;
    float acc = 0.f;
    for (int k = kseg * 256; k < kseg * 256 + 256; k++) {
        float e = emb[b * 1024 + k];
        float se = e / (1.f + __expf(-e));
        acc += se * W[(size_t)k * 1024 + col];
    }
    __shared__ float red[4][64];
    red[kseg][threadIdx.x & 63] = acc;
    __syncthreads();
    if (threadIdx.x < 64)
        out[b * 1024 + blockIdx.x * 64 + threadIdx.x] =
            red[0][threadIdx.x] + red[1][threadIdx.x] + red[2][threadIdx.x] + red[3][threadIdx.x];
}

__global__ __launch_bounds__(256) void k_ada2(const float* __restrict__ t, const float* __restrict__ W,
                                              const float* __restrict__ bias, float* __restrict__ out) {
    int col = blockIdx.x * 64 + (threadIdx.x & 63);
    int b = blockIdx.y;
    int kseg = threadIdx.x >> 6;
    float acc = 0.f;
    for (int k = kseg * 256; k < kseg * 256 + 256; k++)
        acc += t[b * 1024 + k] * W[(size_t)k * 2048 + col];
    __shared__ float red[4][64];
    red[kseg][threadIdx.x & 63] = acc;
    __syncthreads();
    if (threadIdx.x < 64) {
        int c = blockIdx.x * 64 + threadIdx.x;
        out[b * 2048 + c] = red[0][threadIdx.x] + red[1][threadIdx.x] +
                            red[2][threadIdx.x] + red[3][threadIdx.x] + bias[c];
    }
}

// ---------------- weight conversion: z<4 transposed -> [N][K], z>=4 plain ----------------
__global__ __launch_bounds__(256) void k_conv(const float* s0, u16* d0, const float* s1, u16* d1,
                                              const float* s2, u16* d2, const float* s3, u16* d3,
                                              const float* s4, u16* d4, const float* s5, u16* d5) {
    __shared__ u16 tile[64][65];
    const float* s; u16* d;
    switch (blockIdx.z) {
        case 0: s = s0; d = d0; break;
        case 1: s = s1; d = d1; break;
        case 2: s = s2; d = d2; break;
        case 3: s = s3; d = d3; break;
        case 4: s = s4; d = d4; break;
        default: s = s5; d = d5; break;
    }
    int k0 = blockIdx.x * 64, n0 = blockIdx.y * 64;
    int tx = threadIdx.x & 63, ty = threadIdx.x >> 6;
    if (blockIdx.z >= 4) {
        #pragma unroll
        for (int i = 0; i < 16; i++) {
            int kk = ty + 4 * i;
            d[(size_t)(k0 + kk) * 1024 + n0 + tx] = f2bf(s[(size_t)(k0 + kk) * 1024 + n0 + tx]);
        }
        return;
    }
    #pragma unroll
    for (int i = 0; i < 16; i++) {
        int kk = ty + 4 * i;
        tile[kk][tx] = f2bf(s[(size_t)(k0 + kk) * 1024 + n0 + tx]);
    }
    __syncthreads();
    #pragma unroll
    for (int i = 0; i < 16; i++) {
        int nn = ty + 4 * i;
        d[(size_t)(n0 + nn) * 1024 + k0 + tx] = tile[tx][nn];
    }
}

// ---------------- LayerNorm + modulate -> bf16 ; blocks<512 also build cos/sin tables ----------------
__global__ __launch_bounds__(256) void k_ln(const float* __restrict__ x, const float* __restrict__ ada,
                                            u16* __restrict__ xn, const float* __restrict__ rope,
                                            float* __restrict__ cst, float* __restrict__ snt) {
    if (blockIdx.x < 512) {
        int idx = blockIdx.x * 256 + threadIdx.x;   // 131072 = 2048*64
        float sv, cv;
        __sincosf(rope[idx], &sv, &cv);
        cst[idx] = cv; snt[idx] = sv;
    }
    int row = blockIdx.x;
    int b = row >> 11;
    float4 v = ((const float4*)(x + (size_t)row * 1024))[threadIdx.x];
    float s = v.x + v.y + v.z + v.w;
    float ss = v.x * v.x + v.y * v.y + v.z * v.z + v.w * v.w;
    #pragma unroll
    for (int m = 1; m < 64; m <<= 1) { s += __shfl_xor(s, m, 64); ss += __shfl_xor(ss, m, 64); }
    __shared__ float red[2][4];
    int wave = threadIdx.x >> 6, lane = threadIdx.x & 63;
    if (lane == 0) { red[0][wave] = s; red[1][wave] = ss; }
    __syncthreads();
    s = red[0][0] + red[0][1] + red[0][2] + red[0][3];
    ss = red[1][0] + red[1][1] + red[1][2] + red[1][3];
    float mu = s * (1.f / 1024.f);
    float var = ss * (1.f / 1024.f) - mu * mu;
    float rs = rsqrtf(var + 1e-6f);
    int c = threadIdx.x * 4;
    const float* sh = ada + b * 2048;
    const float* sc = ada + b * 2048 + 1024;
    u16x4 r;
    r.x = f2bf((v.x - mu) * rs * (1.f + sc[c + 0]) + sh[c + 0]);
    r.y = f2bf((v.y - mu) * rs * (1.f + sc[c + 1]) + sh[c + 1]);
    r.z = f2bf((v.z - mu) * rs * (1.f + sc[c + 2]) + sh[c + 2]);
    r.w = f2bf((v.w - mu) * rs * (1.f + sc[c + 3]) + sh[c + 3]);
    *(u16x4*)(xn + (size_t)row * 1024 + c) = r;
}

// ---------------- bf16 MFMA GEMM core, XOR-swizzled LDS, async staging ----------------
// MODE 0: bf16 store with scale; MODE 1: fp32 store + residual + gate; MODE 2: qkv (rope on q/k cols)
template <int BM, int BN, int MODE>
DEV void gemm_core(const u16* __restrict__ A, const u16* __restrict__ Bt,
                   u16* __restrict__ Cb, float* __restrict__ Cf,
                   const float* __restrict__ Xres, const float* __restrict__ gate,
                   const float* __restrict__ cst, const float* __restrict__ snt,
                   float scale, int Nn, int K, int m0, int n0) {
    constexpr int MI = BM / 32, NJ = BN / 32;
    __shared__ u16 As[BM][64];
    __shared__ u16 Bs[BN][64];
    int tid = threadIdx.x;
    int lane = tid & 63, wave = tid >> 6;
    int wm = (wave & 1) * (BM / 2), wn = (wave >> 1) * (BN / 2);
    int lr = lane & 15, quad = lane >> 4;
    f32x4 acc[MI][NJ];
    #pragma unroll
    for (int i = 0; i < MI; i++)
        #pragma unroll
        for (int j = 0; j < NJ; j++) acc[i][j] = f32x4{0.f, 0.f, 0.f, 0.f};

    int arow = tid >> 3;
    int acol = (tid & 7) * 8;                         // LDS dst chunk (lane*16B within wave)
    int g8 = (((tid & 7) ^ (arow & 7))) * 8;          // swizzled global source chunk
    int cc[2] = { ((quad ^ (lr & 7))) * 8, (((4 + quad) ^ (lr & 7))) * 8 };

    for (int k0 = 0; k0 < K; k0 += 64) {
        #pragma unroll
        for (int p = 0; p < MI; p++)
            gl_lds16(A + (size_t)(m0 + arow + 32 * p) * K + k0 + g8, &As[arow + 32 * p][acol]);
        #pragma unroll
        for (int p = 0; p < NJ; p++)
            gl_lds16(Bt + (size_t)(n0 + arow + 32 * p) * K + k0 + g8, &Bs[arow + 32 * p][acol]);
        __syncthreads();
        #pragma unroll
        for (int ks = 0; ks < 2; ks++) {
            short8 af[MI], bfr[NJ];
            #pragma unroll
            for (int i = 0; i < MI; i++) af[i] = *(const short8*)(&As[wm + i * 16 + lr][cc[ks]]);
            #pragma unroll
            for (int j = 0; j < NJ; j++) bfr[j] = *(const short8*)(&Bs[wn + j * 16 + lr][cc[ks]]);
            #pragma unroll
            for (int i = 0; i < MI; i++)
                #pragma unroll
                for (int j = 0; j < NJ; j++)
                    acc[i][j] = __builtin_amdgcn_mfma_f32_16x16x32_bf16(af[i], bfr[j], acc[i][j], 0, 0, 0);
        }
        __syncthreads();
    }

    if (MODE == 2 && (n0 + wn) < 2048) {
        // rope on q/k columns: wave spans exactly one 64-wide head block
        #pragma unroll
        for (int i = 0; i < MI; i++)
            #pragma unroll
            for (int jp = 0; jp < 2; jp++)
                #pragma unroll
                for (int r = 0; r < 4; r++) {
                    int row = m0 + wm + i * 16 + quad * 4 + r;
                    int n = row & 2047;
                    int d1 = jp * 16 + lr;
                    float c1 = cst[n * 64 + d1],      s1 = snt[n * 64 + d1];
                    float c2 = cst[n * 64 + d1 + 32], s2 = snt[n * 64 + d1 + 32];
                    float x1 = acc[i][jp][r], x2 = acc[i][jp + 2][r];
                    Cb[(size_t)row * Nn + n0 + wn + d1]      = f2bf(x1 * c1 - x2 * s1);
                    Cb[(size_t)row * Nn + n0 + wn + d1 + 32] = f2bf(x2 * c2 + x1 * s2);
                }
        return;
    }
    #pragma unroll
    for (int i = 0; i < MI; i++)
        #pragma unroll
        for (int j = 0; j < NJ; j++)
            #pragma unroll
            for (int r = 0; r < 4; r++) {
                int row = m0 + wm + i * 16 + quad * 4 + r;
                int col = n0 + wn + j * 16 + lr;
                float v = acc[i][j][r];
                if (MODE == 1) {
                    int b = row >> 11;
                    Cf[(size_t)row * Nn + col] = Xres[(size_t)row * Nn + col] + gate[b * 1024 + col] * v;
                } else {
                    Cb[(size_t)row * Nn + col] = f2bf(v * scale);
                }
            }
}

template <int BM, int BN, int MODE>
__global__ __launch_bounds__(256) void gemm_bt(const u16* __restrict__ A, const u16* __restrict__ Bt,
                                               u16* __restrict__ Cb, float* __restrict__ Cf,
                                               const float* __restrict__ Xres, const float* __restrict__ gate,
                                               const float* __restrict__ cst, const float* __restrict__ snt,
                                               int Nn, int K) {
    gemm_core<BM, BN, MODE>(A, Bt, Cb, Cf, Xres, gate, cst, snt, 1.f, Nn, K,
                            blockIdx.y * BM, blockIdx.x * BN);
}

// two independent 1024^3 folds (z selects); q-fold scaled by 1/8 (softmax scale folded into WqeT)
__global__ __launch_bounds__(256) void gemm_fold(const u16* A0, const u16* B0, u16* C0,
                                                 const u16* A1, const u16* B1, u16* C1) {
    const u16* A = blockIdx.z ? A1 : A0;
    const u16* Bt = blockIdx.z ? B1 : B0;
    u16* C = blockIdx.z ? C1 : C0;
    float scale = blockIdx.z ? 1.0f : 0.125f;
    gemm_core<64, 64, 0>(A, Bt, C, nullptr, nullptr, nullptr, nullptr, nullptr, scale,
                         1024, 1024, blockIdx.y * 64, blockIdx.x * 64);
}

// ---------------- V transpose: qkv[b][n][2048 + h*64+d] -> vt[bh][d][n] ----------------
__global__ __launch_bounds__(256) void k_vtrans(const u16* __restrict__ v, u16* __restrict__ vt) {
    __shared__ u16 tile[64][65];
    int n0 = blockIdx.x * 64;
    int bh = blockIdx.y; int b = bh >> 4, h = bh & 15;
    int tx = threadIdx.x & 63, ty = threadIdx.x >> 6;
    #pragma unroll
    for (int i = 0; i < 16; i++) {
        int nn = ty + 4 * i;
        tile[nn][tx] = v[(size_t)(b * 2048 + n0 + nn) * 3072 + 2048 + h * 64 + tx];
    }
    __syncthreads();
    #pragma unroll
    for (int i = 0; i < 16; i++) {
        int dd = ty + 4 * i;
        vt[((size_t)bh * 64 + dd) * 2048 + n0 + tx] = tile[tx][dd];
    }
}

// ---------------- flash attention: BQ=128, BK=64, K-split x2, deferred softmax ----------------
// Register-staged K/V double buffer: global->VGPR (2-deep prefetch) then ds_write into next LDS
// buffer. Barrier waits only lgkmcnt; each wave's vmcnt wait is private & overlapped with compute.
// Output: unnormalized fp32 O partials + row sums l (combined by k_comb).
__global__ __launch_bounds__(256) void k_attn(const u16* __restrict__ qkv, const u16* __restrict__ vt,
                                              float* __restrict__ paO, float* __restrict__ paL) {
    __shared__ u16 pool[128 * 72];       // Qs view: stride 64 (staged); Pt view: stride 72 (wave-private)
    __shared__ u16 Ks[2][64][64];
    __shared__ u16 Vs[2][64][64];
    int q0 = blockIdx.x * 128;
    int bh = blockIdx.y; int b = bh >> 4, h = bh & 15;
    int z = blockIdx.z;                  // key half
    int kbase = z * 1024;
    int tid = threadIdx.x;
    int lane = tid & 63, wave = tid >> 6;
    int lr = lane & 15, quad = lane >> 4;
    int srow = tid >> 3, scol = (tid & 7) * 8;
    int sg = (((tid & 7) ^ (srow & 7))) * 8;
    int cc[2] = { ((quad ^ (lr & 7))) * 8, (((4 + quad) ^ (lr & 7))) * 8 };

    const u16* kp = qkv + ((size_t)(b * 2048 + kbase + srow)) * 3072 + 1024 + h * 64 + sg;
    const u16* vp = vt + ((size_t)(bh * 64 + srow)) * 2048 + kbase + sg;

    // Q staging (DMA; drained at first barrier)
    #pragma unroll
    for (int p = 0; p < 4; p++)
        gl_lds16(qkv + ((size_t)(b * 2048 + q0 + srow + 32 * p)) * 3072 + h * 64 + sg,
                 pool + (srow + 32 * p) * 64 + scol);

    short8 krA[2], vrA[2], krB[2], vrB[2];
    krA[0] = *(const short8*)(kp);               krA[1] = *(const short8*)(kp + (size_t)32 * 3072);
    vrA[0] = *(const short8*)(vp);               vrA[1] = *(const short8*)(vp + (size_t)32 * 2048);
    __syncthreads();                             // Q (and t0 regs) ready
    short8 qf[2][2];
    #pragma unroll
    for (int rt = 0; rt < 2; rt++)
        #pragma unroll
        for (int ks = 0; ks < 2; ks++)
            qf[rt][ks] = *(const short8*)(pool + (wave * 32 + rt * 16 + lr) * 64 + cc[ks]);
    // t0 -> LDS[0]; t1 -> regs B
    *(short8*)(&Ks[0][srow][scol])      = krA[0];
    *(short8*)(&Ks[0][srow + 32][scol]) = krA[1];
    *(short8*)(&Vs[0][srow][scol])      = vrA[0];
    *(short8*)(&Vs[0][srow + 32][scol]) = vrA[1];
    krB[0] = *(const short8*)(kp + (size_t)64 * 3072);  krB[1] = *(const short8*)(kp + (size_t)96 * 3072);
    vrB[0] = *(const short8*)(vp + 64);                 vrB[1] = *(const short8*)(vp + 64 + (size_t)32 * 2048);
    __syncthreads();

    float l_part[2] = {0.f, 0.f};
    f32x4 oacc[2][4];
    #pragma unroll
    for (int rt = 0; rt < 2; rt++)
        #pragma unroll
        for (int dt = 0; dt < 4; dt++) oacc[rt][dt] = f32x4{0.f, 0.f, 0.f, 0.f};

    auto body = [&](int it, int cur, short8 (&krF)[2], short8 (&vrF)[2],
                    short8 (&krH)[2], short8 (&vrH)[2]) {
        if (it < 14) {   // prefetch t(it+2) into the freed slot
            const u16* kq = kp + (size_t)(it + 2) * 64 * 3072;
            const u16* vq = vp + (it + 2) * 64;
            krF[0] = *(const short8*)(kq);  krF[1] = *(const short8*)(kq + (size_t)32 * 3072);
            vrF[0] = *(const short8*)(vq);  vrF[1] = *(const short8*)(vq + (size_t)32 * 2048);
        }
        // S^T[key][qrow] = mfma(A=K, B=Q)
        f32x4 st[2][4];
        #pragma unroll
        for (int rt = 0; rt < 2; rt++)
            #pragma unroll
            for (int ct = 0; ct < 4; ct++) st[rt][ct] = f32x4{0.f, 0.f, 0.f, 0.f};
        #pragma unroll
        for (int ks = 0; ks < 2; ks++) {
            short8 kf[4];
            #pragma unroll
            for (int ct = 0; ct < 4; ct++)
                kf[ct] = *(const short8*)(&Ks[cur][ct * 16 + lr][cc[ks]]);
            #pragma unroll
            for (int rt = 0; rt < 2; rt++)
                #pragma unroll
                for (int ct = 0; ct < 4; ct++)
                    st[rt][ct] = __builtin_amdgcn_mfma_f32_16x16x32_bf16(kf[ct], qf[rt][ks], st[rt][ct], 0, 0, 0);
        }
        // p = exp(s); per-lane row sums (qrow = lr); packed b64 P-store, Pt[qrow][key] (wave-private)
        #pragma unroll
        for (int rt = 0; rt < 2; rt++)
            #pragma unroll
            for (int ct = 0; ct < 4; ct++) {
                float p0 = __expf(st[rt][ct][0]);
                float p1 = __expf(st[rt][ct][1]);
                float p2 = __expf(st[rt][ct][2]);
                float p3 = __expf(st[rt][ct][3]);
                l_part[rt] += (p0 + p1) + (p2 + p3);
                uint2v w; w.x = pk2(p0, p1); w.y = pk2(p2, p3);
                *(uint2v*)(pool + (wave * 32 + rt * 16 + lr) * 72 + ct * 16 + quad * 4) = w;
            }
        // O += P V
        #pragma unroll
        for (int ks = 0; ks < 2; ks++) {
            short8 pf[2], vf[4];
            #pragma unroll
            for (int rt = 0; rt < 2; rt++)
                pf[rt] = *(const short8*)(pool + (wave * 32 + rt * 16 + lr) * 72 + ks * 32 + quad * 8);
            #pragma unroll
            for (int dt = 0; dt < 4; dt++)
                vf[dt] = *(const short8*)(&Vs[cur][dt * 16 + lr][cc[ks]]);
            #pragma unroll
            for (int rt = 0; rt < 2; rt++)
                #pragma unroll
                for (int dt = 0; dt < 4; dt++)
                    oacc[rt][dt] = __builtin_amdgcn_mfma_f32_16x16x32_bf16(pf[rt], vf[dt], oacc[rt][dt], 0, 0, 0);
        }
        // hand tile t(it+1) to the next LDS buffer (waits this wave's vmcnt only)
        if (it < 15) {
            int nxt = cur ^ 1;
            *(short8*)(&Ks[nxt][srow][scol])      = krH[0];
            *(short8*)(&Ks[nxt][srow + 32][scol]) = krH[1];
            *(short8*)(&Vs[nxt][srow][scol])      = vrH[0];
            *(short8*)(&Vs[nxt][srow + 32][scol]) = vrH[1];
        }
        __syncthreads();
    };

    #pragma unroll 1
    for (int it2 = 0; it2 < 8; ++it2) {
        body(2 * it2,     0, krA, vrA, krB, vrB);
        body(2 * it2 + 1, 1, krB, vrB, krA, vrA);
    }

    // l reduction across quads; store raw sums
    #pragma unroll
    for (int rt = 0; rt < 2; rt++) {
        float l = l_part[rt];
        l += __shfl_xor(l, 16, 64);
        l += __shfl_xor(l, 32, 64);
        if (quad == 0)
            paL[(size_t)z * 65536 + bh * 2048 + q0 + wave * 32 + rt * 16 + lr] = l;
    }
    // unnormalized O partials (fp32)
    float* po = paO + (size_t)z * 4096 * 1024;
    #pragma unroll
    for (int rt = 0; rt < 2; rt++)
        #pragma unroll
        for (int dt = 0; dt < 4; dt++)
            #pragma unroll
            for (int r = 0; r < 4; r++) {
                int row = q0 + wave * 32 + rt * 16 + quad * 4 + r;
                po[((size_t)(b * 2048 + row)) * 1024 + h * 64 + dt * 16 + lr] = oacc[rt][dt][r];
            }
}

// ---------------- combine K-split partials: aob = (O0+O1)/(l0+l1) ----------------
__global__ __launch_bounds__(256) void k_comb(const float* __restrict__ paO, const float* __restrict__ paL,
                                              u16* __restrict__ aob) {
    int row = blockIdx.x;                 // 4096 = b*2048+n
    int b = row >> 11, n = row & 2047;
    int c = threadIdx.x * 4;
    int h = c >> 6;
    float l0 = paL[(b * 16 + h) * 2048 + n];
    float l1 = paL[65536 + (b * 16 + h) * 2048 + n];
    float inv = 1.f / (l0 + l1);
    float4 o0 = *(const float4*)(paO + (size_t)row * 1024 + c);
    float4 o1 = *(const float4*)(paO + (size_t)4096 * 1024 + (size_t)row * 1024 + c);
    u16x4 r;
    r.x = f2bf((o0.x + o1.x) * inv);
    r.y = f2bf((o0.y + o1.y) * inv);
    r.z = f2bf((o0.z + o1.z) * inv);
    r.w = f2bf((o0.w + o1.w) * inv);
    *(u16x4*)(aob + (size_t)row * 1024 + c) = r;
}

// ---------------- launch ----------------
extern "C" void kernel_launch(void* const* d_in, const int* in_sizes, int n_in,
                              void* d_out, int out_size, void* d_ws, size_t ws_size,
                              hipStream_t stream) {
    const float* x     = (const float*)d_in[0];
    const float* emb   = (const float*)d_in[1];
    const float* gate  = (const float*)d_in[2];
    // d_in[3] crossattn_emb: unused by the reference
    const float* rope  = (const float*)d_in[4];
    const float* Wq1   = (const float*)d_in[5];
    const float* Wq2   = (const float*)d_in[6];
    const float* Wk1   = (const float*)d_in[7];
    const float* Wk2   = (const float*)d_in[8];
    const float* Wv    = (const float*)d_in[9];
    const float* Wo    = (const float*)d_in[10];
    const float* Wada1 = (const float*)d_in[11];
    const float* Wada2 = (const float*)d_in[12];
    const float* bada2 = (const float*)d_in[13];
    float* out = (float*)d_out;

    char* ws = (char*)d_ws;
    size_t off = 0;
    auto alloc = [&](size_t bytes) { void* p = ws + off; off += (bytes + 255) & ~(size_t)255; return p; };
    float* t_ada = (float*)alloc(2048 * 4);
    float* ada   = (float*)alloc(4096 * 4);
    float* cst   = (float*)alloc((size_t)131072 * 4);
    float* snt   = (float*)alloc((size_t)131072 * 4);
    u16* xn    = (u16*)alloc((size_t)4096 * 1024 * 2);
    u16* Wq1b  = (u16*)alloc((size_t)1024 * 1024 * 2);
    u16* Wk1b  = (u16*)alloc((size_t)1024 * 1024 * 2);
    u16* Wq2t  = (u16*)alloc((size_t)1024 * 1024 * 2);
    u16* Wk2t  = (u16*)alloc((size_t)1024 * 1024 * 2);
    u16* Wot   = (u16*)alloc((size_t)1024 * 1024 * 2);
    u16* WqkvT = (u16*)alloc((size_t)3072 * 1024 * 2);   // rows: WqeT | WkeT | WvT
    u16* qkvb  = (u16*)alloc((size_t)4096 * 3072 * 2);   // fused q|k|v (q,k already roped)
    u16* vtb   = (u16*)alloc((size_t)4096 * 1024 * 2);
    u16* aob   = (u16*)alloc((size_t)4096 * 1024 * 2);
    float* paO = (float*)alloc((size_t)2 * 4096 * 1024 * 4);
    float* paL = (float*)alloc((size_t)2 * 65536 * 4);
    (void)ws_size; (void)in_sizes; (void)n_in; (void)out_size;

    // adaLN chain
    k_ada1<<<dim3(16, 2), 256, 0, stream>>>(emb, Wada1, t_ada);
    k_ada2<<<dim3(32, 2), 256, 0, stream>>>(t_ada, Wada2, bada2, ada);

    // weights -> bf16 (4 transposed + 2 plain, one dispatch)
    k_conv<<<dim3(16, 16, 6), 256, 0, stream>>>(Wq2, Wq2t, Wk2, Wk2t,
                                                Wv, WqkvT + (size_t)2048 * 1024, Wo, Wot,
                                                Wq1, Wq1b, Wk1, Wk1b);

    // LayerNorm + modulate (+ rope cos/sin tables)
    k_ln<<<4096, 256, 0, stream>>>(x, ada, xn, rope, cst, snt);

    // fold stacked projections (WqeT scaled by 1/8)
    gemm_fold<<<dim3(16, 16, 2), 256, 0, stream>>>(Wq2t, Wq1b, WqkvT,
                                                   Wk2t, Wk1b, WqkvT + (size_t)1024 * 1024);

    // fused QKV projection + rope epilogue: [4096,1024] x [3072,1024]^T -> [4096,3072]
    gemm_bt<128, 128, 2><<<dim3(24, 32), 256, 0, stream>>>(xn, WqkvT, qkvb, nullptr, nullptr, nullptr,
                                                           cst, snt, 3072, 1024);

    // V transpose for PV operand
    k_vtrans<<<dim3(32, 32), 256, 0, stream>>>(qkvb, vtb);

    // flash attention (K-split x2) + combine
    k_attn<<<dim3(16, 32, 2), 256, 0, stream>>>(qkvb, vtb, paO, paL);
    k_comb<<<4096, 256, 0, stream>>>(paO, paL, aob);

    // final projection + gated residual (fp32 out)
    gemm_bt<128, 64, 1><<<dim3(16, 32), 256, 0, stream>>>(aob, Wot, nullptr, out, x, gate,
                                                          nullptr, nullptr, 1024, 1024);
}

// Round 6
// 293.372 us; speedup vs baseline: 1.0448x; 1.0448x over previous
//
#include <hip/hip_runtime.h>
#include <stdint.h>
#include <math.h>

typedef unsigned short u16;
typedef __attribute__((ext_vector_type(8))) short short8;   // 8 x bf16 (4 VGPRs)
typedef __attribute__((ext_vector_type(4))) float f32x4;    // MFMA acc
typedef __attribute__((ext_vector_type(4))) unsigned short u16x4;
typedef __attribute__((ext_vector_type(2))) unsigned int uint2v;

#define DEV static __device__ __forceinline__

DEV u16 f2bf(float f) {
    unsigned u = __builtin_bit_cast(unsigned, f);
    u = u + 0x7fffu + ((u >> 16) & 1u);   // RNE
    return (u16)(u >> 16);
}
DEV float bf2f(u16 s) { return __builtin_bit_cast(float, ((unsigned)s) << 16); }
// pack two f32 -> two bf16 in one dword (round-half-up; values are p=exp2(s)>0)
DEV unsigned pk2(float a, float b) {
    unsigned ua = __builtin_bit_cast(unsigned, a) + 0x8000u;
    unsigned ub = __builtin_bit_cast(unsigned, b) + 0x8000u;
    return (ua >> 16) | (ub & 0xffff0000u);
}
DEV float fexp2(float x) {
#if __has_builtin(__builtin_amdgcn_exp2f)
    return __builtin_amdgcn_exp2f(x);
#else
    return __expf(x * 0.69314718056f);
#endif
}

// async 16B global -> LDS (m97 pattern)
DEV void gl_lds16(const u16* g, u16* l) {
#if __has_builtin(__builtin_amdgcn_global_load_lds)
    __builtin_amdgcn_global_load_lds((const __attribute__((address_space(1))) unsigned int*)g,
                                     (__attribute__((address_space(3))) unsigned int*)l, 16, 0, 0);
#else
    *(short8*)l = *(const short8*)g;
#endif
}

// B=2, N=2048, D=1024, H=16, HD=64

// ---------------- adaLN stage 1 (fp32, silu fused) ----------------
__global__ __launch_bounds__(256) void k_ada1(const float* __restrict__ emb, const float* __restrict__ W,
                                              float* __restrict__ out) {
    int col = blockIdx.x * 64 + (threadIdx.x & 63);
    int b = blockIdx.y;
    int kseg = threadIdx.x >> 6;
    float acc = 0.f;
    for (int k = kseg * 256; k < kseg * 256 + 256; k++) {
        float e = emb[b * 1024 + k];
        float se = e / (1.f + __expf(-e));
        acc += se * W[(size_t)k * 1024 + col];
    }
    __shared__ float red[4][64];
    red[kseg][threadIdx.x & 63] = acc;
    __syncthreads();
    if (threadIdx.x < 64)
        out[b * 1024 + blockIdx.x * 64 + threadIdx.x] =
            red[0][threadIdx.x] + red[1][threadIdx.x] + red[2][threadIdx.x] + red[3][threadIdx.x];
}

// ---------------- prep: z<6 weight conv (0..3 transposed, 4..5 plain); z==6: ada2 + rope tables ----------------
__global__ __launch_bounds__(256) void k_prep(const float* s0, u16* d0, const float* s1, u16* d1,
                                              const float* s2, u16* d2, const float* s3, u16* d3,
                                              const float* s4, u16* d4, const float* s5, u16* d5,
                                              const float* __restrict__ t_ada, const float* __restrict__ Wada2,
                                              const float* __restrict__ bada2, float* __restrict__ ada,
                                              const float* __restrict__ rope,
                                              float* __restrict__ cst, float* __restrict__ snt) {
    __shared__ u16 tile[64][65];
    __shared__ float red[4][64];
    if (blockIdx.z == 6) {
        int flat = blockIdx.y * 16 + blockIdx.x;
        if (flat < 64) {
            // ada2: [2,1024] x [1024,2048] + bias
            int b = flat >> 5, xb = flat & 31;
            int col = xb * 64 + (threadIdx.x & 63);
            int kseg = threadIdx.x >> 6;
            float acc = 0.f;
            for (int k = kseg * 256; k < kseg * 256 + 256; k++)
                acc += t_ada[b * 1024 + k] * Wada2[(size_t)k * 2048 + col];
            red[kseg][threadIdx.x & 63] = acc;
            __syncthreads();
            if (threadIdx.x < 64) {
                int c = xb * 64 + threadIdx.x;
                ada[b * 2048 + c] = red[0][threadIdx.x] + red[1][threadIdx.x] +
                                    red[2][threadIdx.x] + red[3][threadIdx.x] + bada2[c];
            }
        } else if (flat < 192) {
            int idx = (flat - 64) * 1024 + threadIdx.x * 4;   // 131072 = 2048*64
            float4 rv = *(const float4*)(rope + idx);
            float4 cv, sv;
            __sincosf(rv.x, &sv.x, &cv.x);
            __sincosf(rv.y, &sv.y, &cv.y);
            __sincosf(rv.z, &sv.z, &cv.z);
            __sincosf(rv.w, &sv.w, &cv.w);
            *(float4*)(cst + idx) = cv;
            *(float4*)(snt + idx) = sv;
        }
        return;
    }
    const float* s; u16* d;
    switch (blockIdx.z) {
        case 0: s = s0; d = d0; break;
        case 1: s = s1; d = d1; break;
        case 2: s = s2; d = d2; break;
        case 3: s = s3; d = d3; break;
        case 4: s = s4; d = d4; break;
        default: s = s5; d = d5; break;
    }
    int k0 = blockIdx.x * 64, n0 = blockIdx.y * 64;
    int tx = threadIdx.x & 63, ty = threadIdx.x >> 6;
    if (blockIdx.z >= 4) {
        #pragma unroll
        for (int i = 0; i < 16; i++) {
            int kk = ty + 4 * i;
            d[(size_t)(k0 + kk) * 1024 + n0 + tx] = f2bf(s[(size_t)(k0 + kk) * 1024 + n0 + tx]);
        }
        return;
    }
    #pragma unroll
    for (int i = 0; i < 16; i++) {
        int kk = ty + 4 * i;
        tile[kk][tx] = f2bf(s[(size_t)(k0 + kk) * 1024 + n0 + tx]);
    }
    __syncthreads();
    #pragma unroll
    for (int i = 0; i < 16; i++) {
        int nn = ty + 4 * i;
        d[(size_t)(n0 + nn) * 1024 + k0 + tx] = tile[tx][nn];
    }
}

// ---------------- LayerNorm + adaLN modulate -> bf16 ----------------
__global__ __launch_bounds__(256) void k_ln(const float* __restrict__ x, const float* __restrict__ ada,
                                            u16* __restrict__ xn) {
    int row = blockIdx.x;
    int b = row >> 11;
    float4 v = ((const float4*)(x + (size_t)row * 1024))[threadIdx.x];
    float s = v.x + v.y + v.z + v.w;
    float ss = v.x * v.x + v.y * v.y + v.z * v.z + v.w * v.w;
    #pragma unroll
    for (int m = 1; m < 64; m <<= 1) { s += __shfl_xor(s, m, 64); ss += __shfl_xor(ss, m, 64); }
    __shared__ float red[2][4];
    int wave = threadIdx.x >> 6, lane = threadIdx.x & 63;
    if (lane == 0) { red[0][wave] = s; red[1][wave] = ss; }
    __syncthreads();
    s = red[0][0] + red[0][1] + red[0][2] + red[0][3];
    ss = red[1][0] + red[1][1] + red[1][2] + red[1][3];
    float mu = s * (1.f / 1024.f);
    float var = ss * (1.f / 1024.f) - mu * mu;
    float rs = rsqrtf(var + 1e-6f);
    int c = threadIdx.x * 4;
    const float* sh = ada + b * 2048;
    const float* sc = ada + b * 2048 + 1024;
    u16x4 r;
    r.x = f2bf((v.x - mu) * rs * (1.f + sc[c + 0]) + sh[c + 0]);
    r.y = f2bf((v.y - mu) * rs * (1.f + sc[c + 1]) + sh[c + 1]);
    r.z = f2bf((v.z - mu) * rs * (1.f + sc[c + 2]) + sh[c + 2]);
    r.w = f2bf((v.w - mu) * rs * (1.f + sc[c + 3]) + sh[c + 3]);
    *(u16x4*)(xn + (size_t)row * 1024 + c) = r;
}

// ---------------- bf16 MFMA GEMM core, XOR-swizzled LDS, async staging ----------------
// MODE 0: bf16 store with scale; MODE 1: fp32 store + residual + gate;
// MODE 2: qkv epilogue — rope for q/k cols (<2048), transposed vt store for v cols (>=2048)
template <int BM, int BN, int MODE>
DEV void gemm_core(const u16* __restrict__ A, const u16* __restrict__ Bt,
                   u16* __restrict__ Cb, float* __restrict__ Cf, u16* __restrict__ Vt,
                   const float* __restrict__ Xres, const float* __restrict__ gate,
                   const float* __restrict__ cst, const float* __restrict__ snt,
                   float scale, int Nn, int K, int m0, int n0) {
    constexpr int MI = BM / 32, NJ = BN / 32;
    __shared__ u16 As[BM][64];
    __shared__ u16 Bs[BN][64];
    int tid = threadIdx.x;
    int lane = tid & 63, wave = tid >> 6;
    int wm = (wave & 1) * (BM / 2), wn = (wave >> 1) * (BN / 2);
    int lr = lane & 15, quad = lane >> 4;
    f32x4 acc[MI][NJ];
    #pragma unroll
    for (int i = 0; i < MI; i++)
        #pragma unroll
        for (int j = 0; j < NJ; j++) acc[i][j] = f32x4{0.f, 0.f, 0.f, 0.f};

    int arow = tid >> 3;
    int acol = (tid & 7) * 8;                         // LDS dst chunk (lane*16B within wave)
    int g8 = (((tid & 7) ^ (arow & 7))) * 8;          // swizzled global source chunk
    int cc[2] = { ((quad ^ (lr & 7))) * 8, (((4 + quad) ^ (lr & 7))) * 8 };

    for (int k0 = 0; k0 < K; k0 += 64) {
        #pragma unroll
        for (int p = 0; p < MI; p++)
            gl_lds16(A + (size_t)(m0 + arow + 32 * p) * K + k0 + g8, &As[arow + 32 * p][acol]);
        #pragma unroll
        for (int p = 0; p < NJ; p++)
            gl_lds16(Bt + (size_t)(n0 + arow + 32 * p) * K + k0 + g8, &Bs[arow + 32 * p][acol]);
        __syncthreads();
        #pragma unroll
        for (int ks = 0; ks < 2; ks++) {
            short8 af[MI], bfr[NJ];
            #pragma unroll
            for (int i = 0; i < MI; i++) af[i] = *(const short8*)(&As[wm + i * 16 + lr][cc[ks]]);
            #pragma unroll
            for (int j = 0; j < NJ; j++) bfr[j] = *(const short8*)(&Bs[wn + j * 16 + lr][cc[ks]]);
            #pragma unroll
            for (int i = 0; i < MI; i++)
                #pragma unroll
                for (int j = 0; j < NJ; j++)
                    acc[i][j] = __builtin_amdgcn_mfma_f32_16x16x32_bf16(af[i], bfr[j], acc[i][j], 0, 0, 0);
        }
        __syncthreads();
    }

    if (MODE == 2) {
        if ((n0 + wn) < 2048) {
            // rope on q/k columns: wave spans exactly one 64-wide head block
            #pragma unroll
            for (int i = 0; i < MI; i++)
                #pragma unroll
                for (int jp = 0; jp < 2; jp++)
                    #pragma unroll
                    for (int r = 0; r < 4; r++) {
                        int row = m0 + wm + i * 16 + quad * 4 + r;
                        int n = row & 2047;
                        int d1 = jp * 16 + lr;
                        float c1 = cst[n * 64 + d1],      s1 = snt[n * 64 + d1];
                        float c2 = cst[n * 64 + d1 + 32], s2 = snt[n * 64 + d1 + 32];
                        float x1 = acc[i][jp][r], x2 = acc[i][jp + 2][r];
                        Cb[(size_t)row * Nn + n0 + wn + d1]      = f2bf(x1 * c1 - x2 * s1);
                        Cb[(size_t)row * Nn + n0 + wn + d1 + 32] = f2bf(x2 * c2 + x1 * s2);
                    }
        } else {
            // v columns: write transposed vt[bh][d][n] directly (u16x4 over 4 consecutive tokens)
            int hv = (n0 + wn - 2048) >> 6;
            #pragma unroll
            for (int i = 0; i < MI; i++)
                #pragma unroll
                for (int j = 0; j < NJ; j++) {
                    int token = m0 + wm + i * 16 + quad * 4;
                    int bb = token >> 11;
                    int nloc = token & 2047;
                    u16x4 w;
                    w.x = f2bf(acc[i][j][0]); w.y = f2bf(acc[i][j][1]);
                    w.z = f2bf(acc[i][j][2]); w.w = f2bf(acc[i][j][3]);
                    *(u16x4*)(Vt + ((size_t)((bb * 16 + hv) * 64 + j * 16 + lr)) * 2048 + nloc) = w;
                }
        }
        return;
    }
    #pragma unroll
    for (int i = 0; i < MI; i++)
        #pragma unroll
        for (int j = 0; j < NJ; j++)
            #pragma unroll
            for (int r = 0; r < 4; r++) {
                int row = m0 + wm + i * 16 + quad * 4 + r;
                int col = n0 + wn + j * 16 + lr;
                float v = acc[i][j][r];
                if (MODE == 1) {
                    int b = row >> 11;
                    Cf[(size_t)row * Nn + col] = Xres[(size_t)row * Nn + col] + gate[b * 1024 + col] * v;
                } else {
                    Cb[(size_t)row * Nn + col] = f2bf(v * scale);
                }
            }
}

template <int BM, int BN, int MODE>
__global__ __launch_bounds__(256) void gemm_bt(const u16* __restrict__ A, const u16* __restrict__ Bt,
                                               u16* __restrict__ Cb, float* __restrict__ Cf,
                                               u16* __restrict__ Vt,
                                               const float* __restrict__ Xres, const float* __restrict__ gate,
                                               const float* __restrict__ cst, const float* __restrict__ snt,
                                               int Nn, int K) {
    gemm_core<BM, BN, MODE>(A, Bt, Cb, Cf, Vt, Xres, gate, cst, snt, 1.f, Nn, K,
                            blockIdx.y * BM, blockIdx.x * BN);
}

// two independent 1024^3 folds (z selects); q-fold scale = 0.125/ln2 (softmax scale + exp2 domain)
__global__ __launch_bounds__(256) void gemm_fold(const u16* A0, const u16* B0, u16* C0,
                                                 const u16* A1, const u16* B1, u16* C1) {
    const u16* A = blockIdx.z ? A1 : A0;
    const u16* Bt = blockIdx.z ? B1 : B0;
    u16* C = blockIdx.z ? C1 : C0;
    float scale = blockIdx.z ? 1.0f : 0.18033688f;
    gemm_core<64, 64, 0>(A, Bt, C, nullptr, nullptr, nullptr, nullptr, nullptr, nullptr, scale,
                         1024, 1024, blockIdx.y * 64, blockIdx.x * 64);
}

// ---------------- flash attention: BQ=128, BK=64, K-split x2, deferred softmax (exp2 domain) ----------------
// Register-staged K/V double buffer; unnormalized bf16 O partials dumped in thread-linear layout
// (fully coalesced 64B/thread), row sums l to paL. k_comb combines & normalizes.
__global__ __launch_bounds__(256) void k_attn(const u16* __restrict__ qkv, const u16* __restrict__ vt,
                                              u16* __restrict__ dump, float* __restrict__ paL) {
    __shared__ u16 pool[128 * 72];       // Qs view: stride 64 (staged); Pt view: stride 72 (wave-private)
    __shared__ u16 Ks[2][64][64];
    __shared__ u16 Vs[2][64][64];
    int q0 = blockIdx.x * 128;
    int bh = blockIdx.y; int b = bh >> 4, h = bh & 15;
    int z = blockIdx.z;                  // key half
    int kbase = z * 1024;
    int tid = threadIdx.x;
    int lane = tid & 63, wave = tid >> 6;
    int lr = lane & 15, quad = lane >> 4;
    int srow = tid >> 3, scol = (tid & 7) * 8;
    int sg = (((tid & 7) ^ (srow & 7))) * 8;
    int cc[2] = { ((quad ^ (lr & 7))) * 8, (((4 + quad) ^ (lr & 7))) * 8 };

    const u16* kp = qkv + ((size_t)(b * 2048 + kbase + srow)) * 2048 + 1024 + h * 64 + sg;
    const u16* vp = vt + ((size_t)(bh * 64 + srow)) * 2048 + kbase + sg;

    // Q staging (DMA; drained at first barrier)
    #pragma unroll
    for (int p = 0; p < 4; p++)
        gl_lds16(qkv + ((size_t)(b * 2048 + q0 + srow + 32 * p)) * 2048 + h * 64 + sg,
                 pool + (srow + 32 * p) * 64 + scol);

    short8 krA[2], vrA[2], krB[2], vrB[2];
    krA[0] = *(const short8*)(kp);               krA[1] = *(const short8*)(kp + (size_t)32 * 2048);
    vrA[0] = *(const short8*)(vp);               vrA[1] = *(const short8*)(vp + (size_t)32 * 2048);
    __syncthreads();                             // Q (and t0 regs) ready
    short8 qf[2][2];
    #pragma unroll
    for (int rt = 0; rt < 2; rt++)
        #pragma unroll
        for (int ks = 0; ks < 2; ks++)
            qf[rt][ks] = *(const short8*)(pool + (wave * 32 + rt * 16 + lr) * 64 + cc[ks]);
    // t0 -> LDS[0]; t1 -> regs B
    *(short8*)(&Ks[0][srow][scol])      = krA[0];
    *(short8*)(&Ks[0][srow + 32][scol]) = krA[1];
    *(short8*)(&Vs[0][srow][scol])      = vrA[0];
    *(short8*)(&Vs[0][srow + 32][scol]) = vrA[1];
    krB[0] = *(const short8*)(kp + (size_t)64 * 2048);  krB[1] = *(const short8*)(kp + (size_t)96 * 2048);
    vrB[0] = *(const short8*)(vp + 64);                 vrB[1] = *(const short8*)(vp + 64 + (size_t)32 * 2048);
    __syncthreads();

    float l_part[2] = {0.f, 0.f};
    f32x4 oacc[2][4];
    #pragma unroll
    for (int rt = 0; rt < 2; rt++)
        #pragma unroll
        for (int dt = 0; dt < 4; dt++) oacc[rt][dt] = f32x4{0.f, 0.f, 0.f, 0.f};

    auto body = [&](int it, int cur, short8 (&krF)[2], short8 (&vrF)[2],
                    short8 (&krH)[2], short8 (&vrH)[2]) {
        if (it < 14) {   // prefetch t(it+2) into the freed slot
            const u16* kq = kp + (size_t)(it + 2) * 64 * 2048;
            const u16* vq = vp + (it + 2) * 64;
            krF[0] = *(const short8*)(kq);  krF[1] = *(const short8*)(kq + (size_t)32 * 2048);
            vrF[0] = *(const short8*)(vq);  vrF[1] = *(const short8*)(vq + (size_t)32 * 2048);
        }
        // S^T[key][qrow] = mfma(A=K, B=Q)
        f32x4 st[2][4];
        #pragma unroll
        for (int rt = 0; rt < 2; rt++)
            #pragma unroll
            for (int ct = 0; ct < 4; ct++) st[rt][ct] = f32x4{0.f, 0.f, 0.f, 0.f};
        #pragma unroll
        for (int ks = 0; ks < 2; ks++) {
            short8 kf[4];
            #pragma unroll
            for (int ct = 0; ct < 4; ct++)
                kf[ct] = *(const short8*)(&Ks[cur][ct * 16 + lr][cc[ks]]);
            #pragma unroll
            for (int rt = 0; rt < 2; rt++)
                #pragma unroll
                for (int ct = 0; ct < 4; ct++)
                    st[rt][ct] = __builtin_amdgcn_mfma_f32_16x16x32_bf16(kf[ct], qf[rt][ks], st[rt][ct], 0, 0, 0);
        }
        // p = exp2(s); per-lane row sums (qrow = lr); packed b64 P-store, Pt[qrow][key] (wave-private)
        #pragma unroll
        for (int rt = 0; rt < 2; rt++)
            #pragma unroll
            for (int ct = 0; ct < 4; ct++) {
                float p0 = fexp2(st[rt][ct][0]);
                float p1 = fexp2(st[rt][ct][1]);
                float p2 = fexp2(st[rt][ct][2]);
                float p3 = fexp2(st[rt][ct][3]);
                l_part[rt] += (p0 + p1) + (p2 + p3);
                uint2v w; w.x = pk2(p0, p1); w.y = pk2(p2, p3);
                *(uint2v*)(pool + (wave * 32 + rt * 16 + lr) * 72 + ct * 16 + quad * 4) = w;
            }
        // O += P V
        #pragma unroll
        for (int ks = 0; ks < 2; ks++) {
            short8 pf[2], vf[4];
            #pragma unroll
            for (int rt = 0; rt < 2; rt++)
                pf[rt] = *(const short8*)(pool + (wave * 32 + rt * 16 + lr) * 72 + ks * 32 + quad * 8);
            #pragma unroll
            for (int dt = 0; dt < 4; dt++)
                vf[dt] = *(const short8*)(&Vs[cur][dt * 16 + lr][cc[ks]]);
            #pragma unroll
            for (int rt = 0; rt < 2; rt++)
                #pragma unroll
                for (int dt = 0; dt < 4; dt++)
                    oacc[rt][dt] = __builtin_amdgcn_mfma_f32_16x16x32_bf16(pf[rt], vf[dt], oacc[rt][dt], 0, 0, 0);
        }
        // hand tile t(it+1) to the next LDS buffer (waits this wave's vmcnt only)
        if (it < 15) {
            int nxt = cur ^ 1;
            *(short8*)(&Ks[nxt][srow][scol])      = krH[0];
            *(short8*)(&Ks[nxt][srow + 32][scol]) = krH[1];
            *(short8*)(&Vs[nxt][srow][scol])      = vrH[0];
            *(short8*)(&Vs[nxt][srow + 32][scol]) = vrH[1];
        }
        __syncthreads();
    };

    #pragma unroll 1
    for (int it2 = 0; it2 < 8; ++it2) {
        body(2 * it2,     0, krA, vrA, krB, vrB);
        body(2 * it2 + 1, 1, krB, vrB, krA, vrA);
    }

    // l reduction across quads; store raw sums
    #pragma unroll
    for (int rt = 0; rt < 2; rt++) {
        float l = l_part[rt];
        l += __shfl_xor(l, 16, 64);
        l += __shfl_xor(l, 32, 64);
        if (quad == 0)
            paL[(size_t)z * 65536 + bh * 2048 + q0 + wave * 32 + rt * 16 + lr] = l;
    }
    // unnormalized bf16 O partials, thread-linear dump (coalesced 64B/thread)
    u16* dp = dump + (size_t)z * 4194304 + ((size_t)(bh * 16 + blockIdx.x) * 256 + tid) * 32;
    #pragma unroll
    for (int rt = 0; rt < 2; rt++)
        #pragma unroll
        for (int dt = 0; dt < 4; dt++) {
            u16x4 w;
            w.x = f2bf(oacc[rt][dt][0]); w.y = f2bf(oacc[rt][dt][1]);
            w.z = f2bf(oacc[rt][dt][2]); w.w = f2bf(oacc[rt][dt][3]);
            *(u16x4*)(dp + rt * 16 + dt * 4) = w;
        }
}

// ---------------- combine K-split partials: aob = (O0+O1)/(l0+l1); mirrors k_attn's dump layout ----------------
__global__ __launch_bounds__(256) void k_comb(const u16* __restrict__ dump, const float* __restrict__ paL,
                                              u16* __restrict__ aob) {
    int bx = blockIdx.x, bh = blockIdx.y;
    int b = bh >> 4, h = bh & 15;
    int tid = threadIdx.x;
    int lane = tid & 63, wave = tid >> 6;
    int lr = lane & 15, quad = lane >> 4;
    int q0 = bx * 128;
    const u16* d0 = dump + ((size_t)(bh * 16 + bx) * 256 + tid) * 32;
    const u16* d1 = d0 + 4194304;
    #pragma unroll
    for (int rt = 0; rt < 2; rt++) {
        float inv[4];
        #pragma unroll
        for (int r = 0; r < 4; r++) {
            int row = q0 + wave * 32 + rt * 16 + quad * 4 + r;
            float l0 = paL[bh * 2048 + row];
            float l1 = paL[65536 + bh * 2048 + row];
            inv[r] = 1.f / (l0 + l1);
        }
        #pragma unroll
        for (int dt = 0; dt < 4; dt++) {
            u16x4 w0 = *(const u16x4*)(d0 + rt * 16 + dt * 4);
            u16x4 w1 = *(const u16x4*)(d1 + rt * 16 + dt * 4);
            #pragma unroll
            for (int r = 0; r < 4; r++) {
                int row = q0 + wave * 32 + rt * 16 + quad * 4 + r;
                float o = (bf2f(((const u16*)&w0)[r]) + bf2f(((const u16*)&w1)[r])) * inv[r];
                aob[((size_t)(b * 2048 + row)) * 1024 + h * 64 + dt * 16 + lr] = f2bf(o);
            }
        }
    }
}

// ---------------- launch ----------------
extern "C" void kernel_launch(void* const* d_in, const int* in_sizes, int n_in,
                              void* d_out, int out_size, void* d_ws, size_t ws_size,
                              hipStream_t stream) {
    const float* x     = (const float*)d_in[0];
    const float* emb   = (const float*)d_in[1];
    const float* gate  = (const float*)d_in[2];
    // d_in[3] crossattn_emb: unused by the reference
    const float* rope  = (const float*)d_in[4];
    const float* Wq1   = (const float*)d_in[5];
    const float* Wq2   = (const float*)d_in[6];
    const float* Wk1   = (const float*)d_in[7];
    const float* Wk2   = (const float*)d_in[8];
    const float* Wv    = (const float*)d_in[9];
    const float* Wo    = (const float*)d_in[10];
    const float* Wada1 = (const float*)d_in[11];
    const float* Wada2 = (const float*)d_in[12];
    const float* bada2 = (const float*)d_in[13];
    float* out = (float*)d_out;

    char* ws = (char*)d_ws;
    size_t off = 0;
    auto alloc = [&](size_t bytes) { void* p = ws + off; off += (bytes + 255) & ~(size_t)255; return p; };
    float* t_ada = (float*)alloc(2048 * 4);
    float* ada   = (float*)alloc(4096 * 4);
    float* cst   = (float*)alloc((size_t)131072 * 4);
    float* snt   = (float*)alloc((size_t)131072 * 4);
    u16* xn    = (u16*)alloc((size_t)4096 * 1024 * 2);
    u16* Wq1b  = (u16*)alloc((size_t)1024 * 1024 * 2);
    u16* Wk1b  = (u16*)alloc((size_t)1024 * 1024 * 2);
    u16* Wq2t  = (u16*)alloc((size_t)1024 * 1024 * 2);
    u16* Wk2t  = (u16*)alloc((size_t)1024 * 1024 * 2);
    u16* Wot   = (u16*)alloc((size_t)1024 * 1024 * 2);
    u16* WqkvT = (u16*)alloc((size_t)3072 * 1024 * 2);   // rows: WqeT | WkeT | WvT
    u16* qkvb  = (u16*)alloc((size_t)4096 * 2048 * 2);   // q|k (roped), row stride 2048
    u16* vtb   = (u16*)alloc((size_t)4096 * 1024 * 2);   // vt[bh][d][n]
    u16* aob   = (u16*)alloc((size_t)4096 * 1024 * 2);
    u16* dumpO = (u16*)alloc((size_t)2 * 4194304 * 2);   // bf16 O partials, thread-linear
    float* paL = (float*)alloc((size_t)2 * 65536 * 4);
    (void)ws_size; (void)in_sizes; (void)n_in; (void)out_size;

    // adaLN stage 1
    k_ada1<<<dim3(16, 2), 256, 0, stream>>>(emb, Wada1, t_ada);

    // prep: weight conversions + ada2 + rope tables (one dispatch)
    k_prep<<<dim3(16, 16, 7), 256, 0, stream>>>(Wq2, Wq2t, Wk2, Wk2t,
                                                Wv, WqkvT + (size_t)2048 * 1024, Wo, Wot,
                                                Wq1, Wq1b, Wk1, Wk1b,
                                                t_ada, Wada2, bada2, ada, rope, cst, snt);

    // LayerNorm + modulate
    k_ln<<<4096, 256, 0, stream>>>(x, ada, xn);

    // fold stacked projections (WqeT scale = 0.125/ln2 for exp2-domain softmax)
    gemm_fold<<<dim3(16, 16, 2), 256, 0, stream>>>(Wq2t, Wq1b, WqkvT,
                                                   Wk2t, Wk1b, WqkvT + (size_t)1024 * 1024);

    // fused QKV projection + rope epilogue + transposed V store
    gemm_bt<128, 128, 2><<<dim3(24, 32), 256, 0, stream>>>(xn, WqkvT, qkvb, nullptr, vtb,
                                                           nullptr, nullptr, cst, snt, 2048, 1024);

    // flash attention (K-split x2) + combine
    k_attn<<<dim3(16, 32, 2), 256, 0, stream>>>(qkvb, vtb, dumpO, paL);
    k_comb<<<dim3(16, 32), 256, 0, stream>>>(dumpO, paL, aob);

    // final projection + gated residual (fp32 out)
    gemm_bt<128, 64, 1><<<dim3(16, 32), 256, 0, stream>>>(aob, Wot, nullptr, out, nullptr, x, gate,
                                                          nullptr, nullptr, 1024, 1024);
}

// Round 7
// 279.792 us; speedup vs baseline: 1.0955x; 1.0485x over previous
//
#include <hip/hip_runtime.h>
#include <stdint.h>
#include <math.h>

typedef unsigned short u16;
typedef __attribute__((ext_vector_type(8))) short short8;   // 8 x bf16 (4 VGPRs)
typedef __attribute__((ext_vector_type(4))) float f32x4;    // MFMA acc
typedef __attribute__((ext_vector_type(4))) unsigned short u16x4;
typedef __attribute__((ext_vector_type(2))) unsigned int uint2v;

#define DEV static __device__ __forceinline__

DEV u16 f2bf(float f) {
    unsigned u = __builtin_bit_cast(unsigned, f);
    u = u + 0x7fffu + ((u >> 16) & 1u);   // RNE
    return (u16)(u >> 16);
}
DEV float bf2f(u16 s) { return __builtin_bit_cast(float, ((unsigned)s) << 16); }
// pack two f32 -> two bf16 in one dword (round-half-up; values are p=exp2(s)>0)
DEV unsigned pk2(float a, float b) {
    unsigned ua = __builtin_bit_cast(unsigned, a) + 0x8000u;
    unsigned ub = __builtin_bit_cast(unsigned, b) + 0x8000u;
    return (ua >> 16) | (ub & 0xffff0000u);
}
DEV float fexp2(float x) {
#if __has_builtin(__builtin_amdgcn_exp2f)
    return __builtin_amdgcn_exp2f(x);
#else
    return __expf(x * 0.69314718056f);
#endif
}

// async 16B global -> LDS (m97 pattern) — used only for attn's one-shot Q staging
DEV void gl_lds16(const u16* g, u16* l) {
#if __has_builtin(__builtin_amdgcn_global_load_lds)
    __builtin_amdgcn_global_load_lds((const __attribute__((address_space(1))) unsigned int*)g,
                                     (__attribute__((address_space(3))) unsigned int*)l, 16, 0, 0);
#else
    *(short8*)l = *(const short8*)g;
#endif
}

// B=2, N=2048, D=1024, H=16, HD=64

// ---------------- adaLN stage 1 (fp32, silu fused) ----------------
__global__ __launch_bounds__(256) void k_ada1(const float* __restrict__ emb, const float* __restrict__ W,
                                              float* __restrict__ out) {
    int col = blockIdx.x * 64 + (threadIdx.x & 63);
    int b = blockIdx.y;
    int kseg = threadIdx.x >> 6;
    float acc = 0.f;
    for (int k = kseg * 256; k < kseg * 256 + 256; k++) {
        float e = emb[b * 1024 + k];
        float se = e / (1.f + __expf(-e));
        acc += se * W[(size_t)k * 1024 + col];
    }
    __shared__ float red[4][64];
    red[kseg][threadIdx.x & 63] = acc;
    __syncthreads();
    if (threadIdx.x < 64)
        out[b * 1024 + blockIdx.x * 64 + threadIdx.x] =
            red[0][threadIdx.x] + red[1][threadIdx.x] + red[2][threadIdx.x] + red[3][threadIdx.x];
}

// ---------------- prep: z<6 weight conv (0..3 transposed, 4..5 plain); z==6: ada2 + rope tables ----------------
__global__ __launch_bounds__(256) void k_prep(const float* s0, u16* d0, const float* s1, u16* d1,
                                              const float* s2, u16* d2, const float* s3, u16* d3,
                                              const float* s4, u16* d4, const float* s5, u16* d5,
                                              const float* __restrict__ t_ada, const float* __restrict__ Wada2,
                                              const float* __restrict__ bada2, float* __restrict__ ada,
                                              const float* __restrict__ rope,
                                              float* __restrict__ cst, float* __restrict__ snt) {
    __shared__ u16 tile[64][65];
    __shared__ float red[4][64];
    if (blockIdx.z == 6) {
        int flat = blockIdx.y * 16 + blockIdx.x;
        if (flat < 64) {
            // ada2: [2,1024] x [1024,2048] + bias
            int b = flat >> 5, xb = flat & 31;
            int col = xb * 64 + (threadIdx.x & 63);
            int kseg = threadIdx.x >> 6;
            float acc = 0.f;
            for (int k = kseg * 256; k < kseg * 256 + 256; k++)
                acc += t_ada[b * 1024 + k] * Wada2[(size_t)k * 2048 + col];
            red[kseg][threadIdx.x & 63] = acc;
            __syncthreads();
            if (threadIdx.x < 64) {
                int c = xb * 64 + threadIdx.x;
                ada[b * 2048 + c] = red[0][threadIdx.x] + red[1][threadIdx.x] +
                                    red[2][threadIdx.x] + red[3][threadIdx.x] + bada2[c];
            }
        } else if (flat < 192) {
            int idx = (flat - 64) * 1024 + threadIdx.x * 4;   // 131072 = 2048*64
            float4 rv = *(const float4*)(rope + idx);
            float4 cv, sv;
            __sincosf(rv.x, &sv.x, &cv.x);
            __sincosf(rv.y, &sv.y, &cv.y);
            __sincosf(rv.z, &sv.z, &cv.z);
            __sincosf(rv.w, &sv.w, &cv.w);
            *(float4*)(cst + idx) = cv;
            *(float4*)(snt + idx) = sv;
        }
        return;
    }
    const float* s; u16* d;
    switch (blockIdx.z) {
        case 0: s = s0; d = d0; break;
        case 1: s = s1; d = d1; break;
        case 2: s = s2; d = d2; break;
        case 3: s = s3; d = d3; break;
        case 4: s = s4; d = d4; break;
        default: s = s5; d = d5; break;
    }
    int k0 = blockIdx.x * 64, n0 = blockIdx.y * 64;
    int tx = threadIdx.x & 63, ty = threadIdx.x >> 6;
    if (blockIdx.z >= 4) {
        #pragma unroll
        for (int i = 0; i < 16; i++) {
            int kk = ty + 4 * i;
            d[(size_t)(k0 + kk) * 1024 + n0 + tx] = f2bf(s[(size_t)(k0 + kk) * 1024 + n0 + tx]);
        }
        return;
    }
    #pragma unroll
    for (int i = 0; i < 16; i++) {
        int kk = ty + 4 * i;
        tile[kk][tx] = f2bf(s[(size_t)(k0 + kk) * 1024 + n0 + tx]);
    }
    __syncthreads();
    #pragma unroll
    for (int i = 0; i < 16; i++) {
        int nn = ty + 4 * i;
        d[(size_t)(n0 + nn) * 1024 + k0 + tx] = tile[tx][nn];
    }
}

// ---------------- LayerNorm + adaLN modulate -> bf16 ----------------
__global__ __launch_bounds__(256) void k_ln(const float* __restrict__ x, const float* __restrict__ ada,
                                            u16* __restrict__ xn) {
    int row = blockIdx.x;
    int b = row >> 11;
    float4 v = ((const float4*)(x + (size_t)row * 1024))[threadIdx.x];
    float s = v.x + v.y + v.z + v.w;
    float ss = v.x * v.x + v.y * v.y + v.z * v.z + v.w * v.w;
    #pragma unroll
    for (int m = 1; m < 64; m <<= 1) { s += __shfl_xor(s, m, 64); ss += __shfl_xor(ss, m, 64); }
    __shared__ float red[2][4];
    int wave = threadIdx.x >> 6, lane = threadIdx.x & 63;
    if (lane == 0) { red[0][wave] = s; red[1][wave] = ss; }
    __syncthreads();
    s = red[0][0] + red[0][1] + red[0][2] + red[0][3];
    ss = red[1][0] + red[1][1] + red[1][2] + red[1][3];
    float mu = s * (1.f / 1024.f);
    float var = ss * (1.f / 1024.f) - mu * mu;
    float rs = rsqrtf(var + 1e-6f);
    int c = threadIdx.x * 4;
    const float* sh = ada + b * 2048;
    const float* sc = ada + b * 2048 + 1024;
    u16x4 r;
    r.x = f2bf((v.x - mu) * rs * (1.f + sc[c + 0]) + sh[c + 0]);
    r.y = f2bf((v.y - mu) * rs * (1.f + sc[c + 1]) + sh[c + 1]);
    r.z = f2bf((v.z - mu) * rs * (1.f + sc[c + 2]) + sh[c + 2]);
    r.w = f2bf((v.w - mu) * rs * (1.f + sc[c + 3]) + sh[c + 3]);
    *(u16x4*)(xn + (size_t)row * 1024 + c) = r;
}

// ---------------- bf16 MFMA GEMM core, reg-staged double-buffered LDS (attn recipe) ----------------
// Depth-2 global->VGPR prefetch; ds_write_b128 into alternate LDS buffer at iter end; barrier waits
// lgkm only (per-wave vmcnt overlapped with MFMA). K must be 1024 (16 iters of BK=64).
// MODE 0: bf16 store with scale; MODE 1: fp32 store + residual + gate;
// MODE 2: qkv epilogue — rope for q/k cols (<2048), transposed vt store for v cols (>=2048)
template <int BM, int BN, int MODE>
DEV void gemm_core(const u16* __restrict__ A, const u16* __restrict__ Bt,
                   u16* __restrict__ Cb, float* __restrict__ Cf, u16* __restrict__ Vt,
                   const float* __restrict__ Xres, const float* __restrict__ gate,
                   const float* __restrict__ cst, const float* __restrict__ snt,
                   float scale, int Nn, int K, int m0, int n0) {
    constexpr int MI = BM / 32, NJ = BN / 32;
    __shared__ u16 As[2][BM][64];
    __shared__ u16 Bs[2][BN][64];
    int tid = threadIdx.x;
    int lane = tid & 63, wave = tid >> 6;
    int wm = (wave & 1) * (BM / 2), wn = (wave >> 1) * (BN / 2);
    int lr = lane & 15, quad = lane >> 4;
    f32x4 acc[MI][NJ];
    #pragma unroll
    for (int i = 0; i < MI; i++)
        #pragma unroll
        for (int j = 0; j < NJ; j++) acc[i][j] = f32x4{0.f, 0.f, 0.f, 0.f};

    int arow = tid >> 3;
    int acol = (tid & 7) * 8;                         // LDS dst chunk (lane-linear)
    int g8 = (((tid & 7) ^ (arow & 7))) * 8;          // swizzled global source chunk
    int cc[2] = { ((quad ^ (lr & 7))) * 8, (((4 + quad) ^ (lr & 7))) * 8 };

    const u16* ap = A + (size_t)(m0 + arow) * K + g8;
    const u16* bp = Bt + (size_t)(n0 + arow) * K + g8;

    short8 ra[2][MI], rb[2][NJ];
    // t0 -> regs[0]
    #pragma unroll
    for (int p = 0; p < MI; p++) ra[0][p] = *(const short8*)(ap + (size_t)(32 * p) * K);
    #pragma unroll
    for (int p = 0; p < NJ; p++) rb[0][p] = *(const short8*)(bp + (size_t)(32 * p) * K);
    // t0 -> LDS[0]
    #pragma unroll
    for (int p = 0; p < MI; p++) *(short8*)(&As[0][arow + 32 * p][acol]) = ra[0][p];
    #pragma unroll
    for (int p = 0; p < NJ; p++) *(short8*)(&Bs[0][arow + 32 * p][acol]) = rb[0][p];
    // t1 -> regs[1]
    #pragma unroll
    for (int p = 0; p < MI; p++) ra[1][p] = *(const short8*)(ap + 64 + (size_t)(32 * p) * K);
    #pragma unroll
    for (int p = 0; p < NJ; p++) rb[1][p] = *(const short8*)(bp + 64 + (size_t)(32 * p) * K);
    __syncthreads();

    auto body = [&](int it, int cur) {
        if (it + 2 < 16) {   // prefetch t(it+2) into the regs freed by tile it
            const u16* aq = ap + (size_t)(it + 2) * 64;
            const u16* bq = bp + (size_t)(it + 2) * 64;
            #pragma unroll
            for (int p = 0; p < MI; p++) ra[cur][p] = *(const short8*)(aq + (size_t)(32 * p) * K);
            #pragma unroll
            for (int p = 0; p < NJ; p++) rb[cur][p] = *(const short8*)(bq + (size_t)(32 * p) * K);
        }
        #pragma unroll
        for (int ks = 0; ks < 2; ks++) {
            short8 af[MI], bfr[NJ];
            #pragma unroll
            for (int i = 0; i < MI; i++) af[i] = *(const short8*)(&As[cur][wm + i * 16 + lr][cc[ks]]);
            #pragma unroll
            for (int j = 0; j < NJ; j++) bfr[j] = *(const short8*)(&Bs[cur][wn + j * 16 + lr][cc[ks]]);
            #pragma unroll
            for (int i = 0; i < MI; i++)
                #pragma unroll
                for (int j = 0; j < NJ; j++)
                    acc[i][j] = __builtin_amdgcn_mfma_f32_16x16x32_bf16(af[i], bfr[j], acc[i][j], 0, 0, 0);
        }
        if (it + 1 < 16) {   // hand tile t(it+1) to the alternate LDS buffer
            int nxt = cur ^ 1;
            #pragma unroll
            for (int p = 0; p < MI; p++) *(short8*)(&As[nxt][arow + 32 * p][acol]) = ra[nxt][p];
            #pragma unroll
            for (int p = 0; p < NJ; p++) *(short8*)(&Bs[nxt][arow + 32 * p][acol]) = rb[nxt][p];
        }
        __syncthreads();
    };
    #pragma unroll 1
    for (int it2 = 0; it2 < 8; ++it2) {
        body(2 * it2, 0);
        body(2 * it2 + 1, 1);
    }

    if (MODE == 2) {
        if ((n0 + wn) < 2048) {
            // rope on q/k columns: wave spans exactly one 64-wide head block
            #pragma unroll
            for (int i = 0; i < MI; i++)
                #pragma unroll
                for (int jp = 0; jp < 2; jp++)
                    #pragma unroll
                    for (int r = 0; r < 4; r++) {
                        int row = m0 + wm + i * 16 + quad * 4 + r;
                        int n = row & 2047;
                        int d1 = jp * 16 + lr;
                        float c1 = cst[n * 64 + d1],      s1 = snt[n * 64 + d1];
                        float c2 = cst[n * 64 + d1 + 32], s2 = snt[n * 64 + d1 + 32];
                        float x1 = acc[i][jp][r], x2 = acc[i][jp + 2][r];
                        Cb[(size_t)row * Nn + n0 + wn + d1]      = f2bf(x1 * c1 - x2 * s1);
                        Cb[(size_t)row * Nn + n0 + wn + d1 + 32] = f2bf(x2 * c2 + x1 * s2);
                    }
        } else {
            // v columns: write transposed vt[bh][d][n] directly (u16x4 over 4 consecutive tokens)
            int hv = (n0 + wn - 2048) >> 6;
            #pragma unroll
            for (int i = 0; i < MI; i++)
                #pragma unroll
                for (int j = 0; j < NJ; j++) {
                    int token = m0 + wm + i * 16 + quad * 4;
                    int bb = token >> 11;
                    int nloc = token & 2047;
                    u16x4 w;
                    w.x = f2bf(acc[i][j][0]); w.y = f2bf(acc[i][j][1]);
                    w.z = f2bf(acc[i][j][2]); w.w = f2bf(acc[i][j][3]);
                    *(u16x4*)(Vt + ((size_t)((bb * 16 + hv) * 64 + j * 16 + lr)) * 2048 + nloc) = w;
                }
        }
        return;
    }
    #pragma unroll
    for (int i = 0; i < MI; i++)
        #pragma unroll
        for (int j = 0; j < NJ; j++)
            #pragma unroll
            for (int r = 0; r < 4; r++) {
                int row = m0 + wm + i * 16 + quad * 4 + r;
                int col = n0 + wn + j * 16 + lr;
                float v = acc[i][j][r];
                if (MODE == 1) {
                    int b = row >> 11;
                    Cf[(size_t)row * Nn + col] = Xres[(size_t)row * Nn + col] + gate[b * 1024 + col] * v;
                } else {
                    Cb[(size_t)row * Nn + col] = f2bf(v * scale);
                }
            }
}

template <int BM, int BN, int MODE, int WPE>
__global__ __launch_bounds__(256, WPE) void gemm_bt(const u16* __restrict__ A, const u16* __restrict__ Bt,
                                                    u16* __restrict__ Cb, float* __restrict__ Cf,
                                                    u16* __restrict__ Vt,
                                                    const float* __restrict__ Xres, const float* __restrict__ gate,
                                                    const float* __restrict__ cst, const float* __restrict__ snt,
                                                    int Nn, int K) {
    gemm_core<BM, BN, MODE>(A, Bt, Cb, Cf, Vt, Xres, gate, cst, snt, 1.f, Nn, K,
                            blockIdx.y * BM, blockIdx.x * BN);
}

// two independent 1024^3 folds (z selects); q-fold scale = 0.125/ln2 (softmax scale + exp2 domain)
__global__ __launch_bounds__(256, 4) void gemm_fold(const u16* A0, const u16* B0, u16* C0,
                                                    const u16* A1, const u16* B1, u16* C1) {
    const u16* A = blockIdx.z ? A1 : A0;
    const u16* Bt = blockIdx.z ? B1 : B0;
    u16* C = blockIdx.z ? C1 : C0;
    float scale = blockIdx.z ? 1.0f : 0.18033688f;
    gemm_core<64, 64, 0>(A, Bt, C, nullptr, nullptr, nullptr, nullptr, nullptr, nullptr, scale,
                         1024, 1024, blockIdx.y * 64, blockIdx.x * 64);
}

// ---------------- flash attention: BQ=128, BK=64, K-split x2, deferred softmax (exp2 domain) ----------------
__global__ __launch_bounds__(256) void k_attn(const u16* __restrict__ qkv, const u16* __restrict__ vt,
                                              u16* __restrict__ dump, float* __restrict__ paL) {
    __shared__ u16 pool[128 * 72];       // Qs view: stride 64 (staged); Pt view: stride 72 (wave-private)
    __shared__ u16 Ks[2][64][64];
    __shared__ u16 Vs[2][64][64];
    int q0 = blockIdx.x * 128;
    int bh = blockIdx.y; int b = bh >> 4, h = bh & 15;
    int z = blockIdx.z;                  // key half
    int kbase = z * 1024;
    int tid = threadIdx.x;
    int lane = tid & 63, wave = tid >> 6;
    int lr = lane & 15, quad = lane >> 4;
    int srow = tid >> 3, scol = (tid & 7) * 8;
    int sg = (((tid & 7) ^ (srow & 7))) * 8;
    int cc[2] = { ((quad ^ (lr & 7))) * 8, (((4 + quad) ^ (lr & 7))) * 8 };

    const u16* kp = qkv + ((size_t)(b * 2048 + kbase + srow)) * 2048 + 1024 + h * 64 + sg;
    const u16* vp = vt + ((size_t)(bh * 64 + srow)) * 2048 + kbase + sg;

    // Q staging (DMA; drained at first barrier)
    #pragma unroll
    for (int p = 0; p < 4; p++)
        gl_lds16(qkv + ((size_t)(b * 2048 + q0 + srow + 32 * p)) * 2048 + h * 64 + sg,
                 pool + (srow + 32 * p) * 64 + scol);

    short8 krA[2], vrA[2], krB[2], vrB[2];
    krA[0] = *(const short8*)(kp);               krA[1] = *(const short8*)(kp + (size_t)32 * 2048);
    vrA[0] = *(const short8*)(vp);               vrA[1] = *(const short8*)(vp + (size_t)32 * 2048);
    __syncthreads();                             // Q (and t0 regs) ready
    short8 qf[2][2];
    #pragma unroll
    for (int rt = 0; rt < 2; rt++)
        #pragma unroll
        for (int ks = 0; ks < 2; ks++)
            qf[rt][ks] = *(const short8*)(pool + (wave * 32 + rt * 16 + lr) * 64 + cc[ks]);
    // t0 -> LDS[0]; t1 -> regs B
    *(short8*)(&Ks[0][srow][scol])      = krA[0];
    *(short8*)(&Ks[0][srow + 32][scol]) = krA[1];
    *(short8*)(&Vs[0][srow][scol])      = vrA[0];
    *(short8*)(&Vs[0][srow + 32][scol]) = vrA[1];
    krB[0] = *(const short8*)(kp + (size_t)64 * 2048);  krB[1] = *(const short8*)(kp + (size_t)96 * 2048);
    vrB[0] = *(const short8*)(vp + 64);                 vrB[1] = *(const short8*)(vp + 64 + (size_t)32 * 2048);
    __syncthreads();

    float l_part[2] = {0.f, 0.f};
    f32x4 oacc[2][4];
    #pragma unroll
    for (int rt = 0; rt < 2; rt++)
        #pragma unroll
        for (int dt = 0; dt < 4; dt++) oacc[rt][dt] = f32x4{0.f, 0.f, 0.f, 0.f};

    auto body = [&](int it, int cur, short8 (&krF)[2], short8 (&vrF)[2],
                    short8 (&krH)[2], short8 (&vrH)[2]) {
        if (it < 14) {   // prefetch t(it+2) into the freed slot
            const u16* kq = kp + (size_t)(it + 2) * 64 * 2048;
            const u16* vq = vp + (it + 2) * 64;
            krF[0] = *(const short8*)(kq);  krF[1] = *(const short8*)(kq + (size_t)32 * 2048);
            vrF[0] = *(const short8*)(vq);  vrF[1] = *(const short8*)(vq + (size_t)32 * 2048);
        }
        // S^T[key][qrow] = mfma(A=K, B=Q)
        f32x4 st[2][4];
        #pragma unroll
        for (int rt = 0; rt < 2; rt++)
            #pragma unroll
            for (int ct = 0; ct < 4; ct++) st[rt][ct] = f32x4{0.f, 0.f, 0.f, 0.f};
        #pragma unroll
        for (int ks = 0; ks < 2; ks++) {
            short8 kf[4];
            #pragma unroll
            for (int ct = 0; ct < 4; ct++)
                kf[ct] = *(const short8*)(&Ks[cur][ct * 16 + lr][cc[ks]]);
            #pragma unroll
            for (int rt = 0; rt < 2; rt++)
                #pragma unroll
                for (int ct = 0; ct < 4; ct++)
                    st[rt][ct] = __builtin_amdgcn_mfma_f32_16x16x32_bf16(kf[ct], qf[rt][ks], st[rt][ct], 0, 0, 0);
        }
        // p = exp2(s); per-lane row sums (qrow = lr); packed b64 P-store, Pt[qrow][key] (wave-private)
        #pragma unroll
        for (int rt = 0; rt < 2; rt++)
            #pragma unroll
            for (int ct = 0; ct < 4; ct++) {
                float p0 = fexp2(st[rt][ct][0]);
                float p1 = fexp2(st[rt][ct][1]);
                float p2 = fexp2(st[rt][ct][2]);
                float p3 = fexp2(st[rt][ct][3]);
                l_part[rt] += (p0 + p1) + (p2 + p3);
                uint2v w; w.x = pk2(p0, p1); w.y = pk2(p2, p3);
                *(uint2v*)(pool + (wave * 32 + rt * 16 + lr) * 72 + ct * 16 + quad * 4) = w;
            }
        // O += P V
        #pragma unroll
        for (int ks = 0; ks < 2; ks++) {
            short8 pf[2], vf[4];
            #pragma unroll
            for (int rt = 0; rt < 2; rt++)
                pf[rt] = *(const short8*)(pool + (wave * 32 + rt * 16 + lr) * 72 + ks * 32 + quad * 8);
            #pragma unroll
            for (int dt = 0; dt < 4; dt++)
                vf[dt] = *(const short8*)(&Vs[cur][dt * 16 + lr][cc[ks]]);
            #pragma unroll
            for (int rt = 0; rt < 2; rt++)
                #pragma unroll
                for (int dt = 0; dt < 4; dt++)
                    oacc[rt][dt] = __builtin_amdgcn_mfma_f32_16x16x32_bf16(pf[rt], vf[dt], oacc[rt][dt], 0, 0, 0);
        }
        // hand tile t(it+1) to the next LDS buffer (waits this wave's vmcnt only)
        if (it < 15) {
            int nxt = cur ^ 1;
            *(short8*)(&Ks[nxt][srow][scol])      = krH[0];
            *(short8*)(&Ks[nxt][srow + 32][scol]) = krH[1];
            *(short8*)(&Vs[nxt][srow][scol])      = vrH[0];
            *(short8*)(&Vs[nxt][srow + 32][scol]) = vrH[1];
        }
        __syncthreads();
    };

    #pragma unroll 1
    for (int it2 = 0; it2 < 8; ++it2) {
        body(2 * it2,     0, krA, vrA, krB, vrB);
        body(2 * it2 + 1, 1, krB, vrB, krA, vrA);
    }

    // l reduction across quads; store raw sums
    #pragma unroll
    for (int rt = 0; rt < 2; rt++) {
        float l = l_part[rt];
        l += __shfl_xor(l, 16, 64);
        l += __shfl_xor(l, 32, 64);
        if (quad == 0)
            paL[(size_t)z * 65536 + bh * 2048 + q0 + wave * 32 + rt * 16 + lr] = l;
    }
    // unnormalized bf16 O partials, thread-linear dump (coalesced 64B/thread)
    u16* dp = dump + (size_t)z * 4194304 + ((size_t)(bh * 16 + blockIdx.x) * 256 + tid) * 32;
    #pragma unroll
    for (int rt = 0; rt < 2; rt++)
        #pragma unroll
        for (int dt = 0; dt < 4; dt++) {
            u16x4 w;
            w.x = f2bf(oacc[rt][dt][0]); w.y = f2bf(oacc[rt][dt][1]);
            w.z = f2bf(oacc[rt][dt][2]); w.w = f2bf(oacc[rt][dt][3]);
            *(u16x4*)(dp + rt * 16 + dt * 4) = w;
        }
}

// ---------------- combine K-split partials: aob = (O0+O1)/(l0+l1); mirrors k_attn's dump layout ----------------
__global__ __launch_bounds__(256) void k_comb(const u16* __restrict__ dump, const float* __restrict__ paL,
                                              u16* __restrict__ aob) {
    int bx = blockIdx.x, bh = blockIdx.y;
    int b = bh >> 4, h = bh & 15;
    int tid = threadIdx.x;
    int lane = tid & 63, wave = tid >> 6;
    int lr = lane & 15, quad = lane >> 4;
    int q0 = bx * 128;
    const u16* d0 = dump + ((size_t)(bh * 16 + bx) * 256 + tid) * 32;
    const u16* d1 = d0 + 4194304;
    #pragma unroll
    for (int rt = 0; rt < 2; rt++) {
        float inv[4];
        #pragma unroll
        for (int r = 0; r < 4; r++) {
            int row = q0 + wave * 32 + rt * 16 + quad * 4 + r;
            float l0 = paL[bh * 2048 + row];
            float l1 = paL[65536 + bh * 2048 + row];
            inv[r] = 1.f / (l0 + l1);
        }
        #pragma unroll
        for (int dt = 0; dt < 4; dt++) {
            u16x4 w0 = *(const u16x4*)(d0 + rt * 16 + dt * 4);
            u16x4 w1 = *(const u16x4*)(d1 + rt * 16 + dt * 4);
            #pragma unroll
            for (int r = 0; r < 4; r++) {
                int row = q0 + wave * 32 + rt * 16 + quad * 4 + r;
                float o = (bf2f(((const u16*)&w0)[r]) + bf2f(((const u16*)&w1)[r])) * inv[r];
                aob[((size_t)(b * 2048 + row)) * 1024 + h * 64 + dt * 16 + lr] = f2bf(o);
            }
        }
    }
}

// ---------------- launch ----------------
extern "C" void kernel_launch(void* const* d_in, const int* in_sizes, int n_in,
                              void* d_out, int out_size, void* d_ws, size_t ws_size,
                              hipStream_t stream) {
    const float* x     = (const float*)d_in[0];
    const float* emb   = (const float*)d_in[1];
    const float* gate  = (const float*)d_in[2];
    // d_in[3] crossattn_emb: unused by the reference
    const float* rope  = (const float*)d_in[4];
    const float* Wq1   = (const float*)d_in[5];
    const float* Wq2   = (const float*)d_in[6];
    const float* Wk1   = (const float*)d_in[7];
    const float* Wk2   = (const float*)d_in[8];
    const float* Wv    = (const float*)d_in[9];
    const float* Wo    = (const float*)d_in[10];
    const float* Wada1 = (const float*)d_in[11];
    const float* Wada2 = (const float*)d_in[12];
    const float* bada2 = (const float*)d_in[13];
    float* out = (float*)d_out;

    char* ws = (char*)d_ws;
    size_t off = 0;
    auto alloc = [&](size_t bytes) { void* p = ws + off; off += (bytes + 255) & ~(size_t)255; return p; };
    float* t_ada = (float*)alloc(2048 * 4);
    float* ada   = (float*)alloc(4096 * 4);
    float* cst   = (float*)alloc((size_t)131072 * 4);
    float* snt   = (float*)alloc((size_t)131072 * 4);
    u16* xn    = (u16*)alloc((size_t)4096 * 1024 * 2);
    u16* Wq1b  = (u16*)alloc((size_t)1024 * 1024 * 2);
    u16* Wk1b  = (u16*)alloc((size_t)1024 * 1024 * 2);
    u16* Wq2t  = (u16*)alloc((size_t)1024 * 1024 * 2);
    u16* Wk2t  = (u16*)alloc((size_t)1024 * 1024 * 2);
    u16* Wot   = (u16*)alloc((size_t)1024 * 1024 * 2);
    u16* WqkvT = (u16*)alloc((size_t)3072 * 1024 * 2);   // rows: WqeT | WkeT | WvT
    u16* qkvb  = (u16*)alloc((size_t)4096 * 2048 * 2);   // q|k (roped), row stride 2048
    u16* vtb   = (u16*)alloc((size_t)4096 * 1024 * 2);   // vt[bh][d][n]
    u16* aob   = (u16*)alloc((size_t)4096 * 1024 * 2);
    u16* dumpO = (u16*)alloc((size_t)2 * 4194304 * 2);   // bf16 O partials, thread-linear
    float* paL = (float*)alloc((size_t)2 * 65536 * 4);
    (void)ws_size; (void)in_sizes; (void)n_in; (void)out_size;

    // adaLN stage 1
    k_ada1<<<dim3(16, 2), 256, 0, stream>>>(emb, Wada1, t_ada);

    // prep: weight conversions + ada2 + rope tables (one dispatch)
    k_prep<<<dim3(16, 16, 7), 256, 0, stream>>>(Wq2, Wq2t, Wk2, Wk2t,
                                                Wv, WqkvT + (size_t)2048 * 1024, Wo, Wot,
                                                Wq1, Wq1b, Wk1, Wk1b,
                                                t_ada, Wada2, bada2, ada, rope, cst, snt);

    // LayerNorm + modulate
    k_ln<<<4096, 256, 0, stream>>>(x, ada, xn);

    // fold stacked projections (WqeT scale = 0.125/ln2 for exp2-domain softmax)
    gemm_fold<<<dim3(16, 16, 2), 256, 0, stream>>>(Wq2t, Wq1b, WqkvT,
                                                   Wk2t, Wk1b, WqkvT + (size_t)1024 * 1024);

    // fused QKV projection + rope epilogue + transposed V store (dbuf, 2 waves/EU)
    gemm_bt<128, 128, 2, 2><<<dim3(24, 32), 256, 0, stream>>>(xn, WqkvT, qkvb, nullptr, vtb,
                                                              nullptr, nullptr, cst, snt, 2048, 1024);

    // flash attention (K-split x2) + combine
    k_attn<<<dim3(16, 32, 2), 256, 0, stream>>>(qkvb, vtb, dumpO, paL);
    k_comb<<<dim3(16, 32), 256, 0, stream>>>(dumpO, paL, aob);

    // final projection + gated residual (fp32 out, dbuf, 3 waves/EU)
    gemm_bt<128, 64, 1, 3><<<dim3(16, 32), 256, 0, stream>>>(aob, Wot, nullptr, out, nullptr, x, gate,
                                                             nullptr, nullptr, 1024, 1024);
}

// Round 8
// 273.642 us; speedup vs baseline: 1.1201x; 1.0225x over previous
//
#include <hip/hip_runtime.h>
#include <stdint.h>
#include <math.h>

typedef unsigned short u16;
typedef __attribute__((ext_vector_type(8))) short short8;   // 8 x bf16 (4 VGPRs)
typedef __attribute__((ext_vector_type(4))) float f32x4;    // MFMA acc
typedef __attribute__((ext_vector_type(4))) unsigned short u16x4;
typedef __attribute__((ext_vector_type(2))) unsigned int uint2v;

#define DEV static __device__ __forceinline__

DEV u16 f2bf(float f) {
    unsigned u = __builtin_bit_cast(unsigned, f);
    u = u + 0x7fffu + ((u >> 16) & 1u);   // RNE
    return (u16)(u >> 16);
}
DEV float bf2f(u16 s) { return __builtin_bit_cast(float, ((unsigned)s) << 16); }
// pack two f32 -> two bf16 in one dword (round-half-up; values are p=exp2(s)>0)
DEV unsigned pk2(float a, float b) {
    unsigned ua = __builtin_bit_cast(unsigned, a) + 0x8000u;
    unsigned ub = __builtin_bit_cast(unsigned, b) + 0x8000u;
    return (ua >> 16) | (ub & 0xffff0000u);
}
DEV float fexp2(float x) {
#if __has_builtin(__builtin_amdgcn_exp2f)
    return __builtin_amdgcn_exp2f(x);
#else
    return __expf(x * 0.69314718056f);
#endif
}

// async 16B global -> LDS — attn's one-shot Q staging only
DEV void gl_lds16(const u16* g, u16* l) {
#if __has_builtin(__builtin_amdgcn_global_load_lds)
    __builtin_amdgcn_global_load_lds((const __attribute__((address_space(1))) unsigned int*)g,
                                     (__attribute__((address_space(3))) unsigned int*)l, 16, 0, 0);
#else
    *(short8*)l = *(const short8*)g;
#endif
}

// B=2, N=2048, D=1024, H=16, HD=64

// ---------------- adaLN stage 1 (fp32, silu fused, 8-way K-split via atomics) ----------------
__global__ __launch_bounds__(256) void k_ada1(const float* __restrict__ emb, const float* __restrict__ W,
                                              float* __restrict__ out) {
    int col = blockIdx.x * 64 + (threadIdx.x & 63);
    int b = blockIdx.y;
    int kbase = blockIdx.z * 128 + (threadIdx.x >> 6) * 32;
    float acc = 0.f;
    for (int k = kbase; k < kbase + 32; k++) {
        float e = emb[b * 1024 + k];
        float se = e / (1.f + __expf(-e));
        acc += se * W[(size_t)k * 1024 + col];
    }
    __shared__ float red[4][64];
    red[threadIdx.x >> 6][threadIdx.x & 63] = acc;
    __syncthreads();
    if (threadIdx.x < 64)
        atomicAdd(out + b * 1024 + blockIdx.x * 64 + threadIdx.x,
                  red[0][threadIdx.x] + red[1][threadIdx.x] + red[2][threadIdx.x] + red[3][threadIdx.x]);
}

// ---------------- prep: z<6 weight conv (0..3 transposed, 4..5 plain); z==6 ada2 (atomic ksplit); z==7 sincos ----
__global__ __launch_bounds__(256) void k_prep(const float* s0, u16* d0, const float* s1, u16* d1,
                                              const float* s2, u16* d2, const float* s3, u16* d3,
                                              const float* s4, u16* d4, const float* s5, u16* d5,
                                              const float* __restrict__ t_ada, const float* __restrict__ Wada2,
                                              float* __restrict__ ada, const float* __restrict__ rope,
                                              float* __restrict__ cst, float* __restrict__ snt) {
    __shared__ u16 tile[64][65];
    __shared__ float red[4][64];
    if (blockIdx.z == 6) {
        int flat = blockIdx.y * 16 + blockIdx.x;       // 0..255
        int kq = flat >> 6;                            // 4-way K-split
        int rest = flat & 63;
        int b = rest >> 5, xb = rest & 31;
        int col = xb * 64 + (threadIdx.x & 63);
        int kbase = kq * 256 + (threadIdx.x >> 6) * 64;
        float acc = 0.f;
        for (int k = kbase; k < kbase + 64; k++)
            acc += t_ada[b * 1024 + k] * Wada2[(size_t)k * 2048 + col];
        red[threadIdx.x >> 6][threadIdx.x & 63] = acc;
        __syncthreads();
        if (threadIdx.x < 64)
            atomicAdd(ada + b * 2048 + xb * 64 + threadIdx.x,
                      red[0][threadIdx.x] + red[1][threadIdx.x] + red[2][threadIdx.x] + red[3][threadIdx.x]);
        return;
    }
    if (blockIdx.z == 7) {
        int flat = blockIdx.y * 16 + blockIdx.x;
        if (flat < 128) {
            int idx = flat * 1024 + threadIdx.x * 4;   // 131072 = 2048*64
            float4 rv = *(const float4*)(rope + idx);
            float4 cv, sv;
            __sincosf(rv.x, &sv.x, &cv.x);
            __sincosf(rv.y, &sv.y, &cv.y);
            __sincosf(rv.z, &sv.z, &cv.z);
            __sincosf(rv.w, &sv.w, &cv.w);
            *(float4*)(cst + idx) = cv;
            *(float4*)(snt + idx) = sv;
        }
        return;
    }
    const float* s; u16* d;
    switch (blockIdx.z) {
        case 0: s = s0; d = d0; break;
        case 1: s = s1; d = d1; break;
        case 2: s = s2; d = d2; break;
        case 3: s = s3; d = d3; break;
        case 4: s = s4; d = d4; break;
        default: s = s5; d = d5; break;
    }
    int k0 = blockIdx.x * 64, n0 = blockIdx.y * 64;
    int tx = threadIdx.x & 63, ty = threadIdx.x >> 6;
    if (blockIdx.z >= 4) {
        #pragma unroll
        for (int i = 0; i < 16; i++) {
            int kk = ty + 4 * i;
            d[(size_t)(k0 + kk) * 1024 + n0 + tx] = f2bf(s[(size_t)(k0 + kk) * 1024 + n0 + tx]);
        }
        return;
    }
    #pragma unroll
    for (int i = 0; i < 16; i++) {
        int kk = ty + 4 * i;
        tile[kk][tx] = f2bf(s[(size_t)(k0 + kk) * 1024 + n0 + tx]);
    }
    __syncthreads();
    #pragma unroll
    for (int i = 0; i < 16; i++) {
        int nn = ty + 4 * i;
        d[(size_t)(n0 + nn) * 1024 + k0 + tx] = tile[tx][nn];
    }
}

// ---------------- LayerNorm + adaLN modulate (ada2 bias folded here) -> bf16 ----------------
__global__ __launch_bounds__(256) void k_ln(const float* __restrict__ x, const float* __restrict__ ada,
                                            const float* __restrict__ bada2, u16* __restrict__ xn) {
    int row = blockIdx.x;
    int b = row >> 11;
    float4 v = ((const float4*)(x + (size_t)row * 1024))[threadIdx.x];
    float s = v.x + v.y + v.z + v.w;
    float ss = v.x * v.x + v.y * v.y + v.z * v.z + v.w * v.w;
    #pragma unroll
    for (int m = 1; m < 64; m <<= 1) { s += __shfl_xor(s, m, 64); ss += __shfl_xor(ss, m, 64); }
    __shared__ float red[2][4];
    int wave = threadIdx.x >> 6, lane = threadIdx.x & 63;
    if (lane == 0) { red[0][wave] = s; red[1][wave] = ss; }
    __syncthreads();
    s = red[0][0] + red[0][1] + red[0][2] + red[0][3];
    ss = red[1][0] + red[1][1] + red[1][2] + red[1][3];
    float mu = s * (1.f / 1024.f);
    float var = ss * (1.f / 1024.f) - mu * mu;
    float rs = rsqrtf(var + 1e-6f);
    int c = threadIdx.x * 4;
    const float* sh = ada + b * 2048;
    const float* sc = ada + b * 2048 + 1024;
    u16x4 r;
    r.x = f2bf((v.x - mu) * rs * (1.f + sc[c + 0] + bada2[1024 + c + 0]) + sh[c + 0] + bada2[c + 0]);
    r.y = f2bf((v.y - mu) * rs * (1.f + sc[c + 1] + bada2[1024 + c + 1]) + sh[c + 1] + bada2[c + 1]);
    r.z = f2bf((v.z - mu) * rs * (1.f + sc[c + 2] + bada2[1024 + c + 2]) + sh[c + 2] + bada2[c + 2]);
    r.w = f2bf((v.w - mu) * rs * (1.f + sc[c + 3] + bada2[1024 + c + 3]) + sh[c + 3] + bada2[c + 3]);
    *(u16x4*)(xn + (size_t)row * 1024 + c) = r;
}

// ---------------- bf16 MFMA GEMM core: BK=32, padded LDS (stride 40), reg-staged dbuf ----------------
// Depth-2 global->VGPR prefetch; ds_write_b128 into alternate padded LDS buffer; barrier waits lgkm
// only. K fixed at 1024 (32 iters of BK=32). No swizzle needed (pad kills conflicts).
// MODE 0: bf16 store with scale; MODE 1: fp32 store + residual + gate;
// MODE 2: qkv epilogue — rope for q/k cols (<2048), LDS-transposed coalesced vt store for v cols.
template <int BM, int BN, int MODE>
DEV void gemm_core(const u16* __restrict__ A, const u16* __restrict__ Bt,
                   u16* __restrict__ Cb, float* __restrict__ Cf, u16* __restrict__ Vt,
                   const float* __restrict__ Xres, const float* __restrict__ gate,
                   const float* __restrict__ cst, const float* __restrict__ snt,
                   float scale, int Nn, int K, int m0, int n0) {
    constexpr int MI = BM / 32, NJ = BN / 32;
    constexpr int PA = BM / 64, PB = BN / 64;
    constexpr int LA = BM * 40, LB = BN * 40;
    __shared__ u16 smem[2 * (LA + LB)];
    int tid = threadIdx.x;
    int lane = tid & 63, wave = tid >> 6;
    int wm = (wave & 1) * (BM / 2), wn = (wave >> 1) * (BN / 2);
    int lr = lane & 15, quad = lane >> 4;
    f32x4 acc[MI][NJ];
    #pragma unroll
    for (int i = 0; i < MI; i++)
        #pragma unroll
        for (int j = 0; j < NJ; j++) acc[i][j] = f32x4{0.f, 0.f, 0.f, 0.f};

    int arow = tid >> 2;                 // 4 threads/row, 64 rows/pass
    int achunk = (tid & 3) * 8;          // 16B chunk within 32-col tile
    const u16* ap = A + (size_t)(m0 + arow) * K + achunk;
    const u16* bp = Bt + (size_t)(n0 + arow) * K + achunk;
    u16* AsL[2] = { smem, smem + LA };
    u16* BsL[2] = { smem + 2 * LA, smem + 2 * LA + LB };

    short8 ra[2][PA], rb[2][PB];
    #pragma unroll
    for (int p = 0; p < PA; p++) ra[0][p] = *(const short8*)(ap + (size_t)(64 * p) * K);
    #pragma unroll
    for (int p = 0; p < PB; p++) rb[0][p] = *(const short8*)(bp + (size_t)(64 * p) * K);
    #pragma unroll
    for (int p = 0; p < PA; p++) *(short8*)(&AsL[0][(arow + 64 * p) * 40 + achunk]) = ra[0][p];
    #pragma unroll
    for (int p = 0; p < PB; p++) *(short8*)(&BsL[0][(arow + 64 * p) * 40 + achunk]) = rb[0][p];
    #pragma unroll
    for (int p = 0; p < PA; p++) ra[1][p] = *(const short8*)(ap + 32 + (size_t)(64 * p) * K);
    #pragma unroll
    for (int p = 0; p < PB; p++) rb[1][p] = *(const short8*)(bp + 32 + (size_t)(64 * p) * K);
    __syncthreads();

    auto body = [&](int it, int cur) {
        if (it + 2 < 32) {
            int koff = (it + 2) * 32;
            #pragma unroll
            for (int p = 0; p < PA; p++) ra[cur][p] = *(const short8*)(ap + koff + (size_t)(64 * p) * K);
            #pragma unroll
            for (int p = 0; p < PB; p++) rb[cur][p] = *(const short8*)(bp + koff + (size_t)(64 * p) * K);
        }
        short8 af[MI], bfr[NJ];
        #pragma unroll
        for (int i = 0; i < MI; i++) af[i] = *(const short8*)(&AsL[cur][(wm + i * 16 + lr) * 40 + quad * 8]);
        #pragma unroll
        for (int j = 0; j < NJ; j++) bfr[j] = *(const short8*)(&BsL[cur][(wn + j * 16 + lr) * 40 + quad * 8]);
        #pragma unroll
        for (int i = 0; i < MI; i++)
            #pragma unroll
            for (int j = 0; j < NJ; j++)
                acc[i][j] = __builtin_amdgcn_mfma_f32_16x16x32_bf16(af[i], bfr[j], acc[i][j], 0, 0, 0);
        if (it + 1 < 32) {
            int nxt = cur ^ 1;
            #pragma unroll
            for (int p = 0; p < PA; p++) *(short8*)(&AsL[nxt][(arow + 64 * p) * 40 + achunk]) = ra[nxt][p];
            #pragma unroll
            for (int p = 0; p < PB; p++) *(short8*)(&BsL[nxt][(arow + 64 * p) * 40 + achunk]) = rb[nxt][p];
        }
        __syncthreads();
    };
    #pragma unroll 1
    for (int it2 = 0; it2 < 16; ++it2) {
        body(2 * it2, 0);
        body(2 * it2 + 1, 1);
    }

    if (MODE == 2) {
        if ((n0 + wn) < 2048) {
            // rope on q/k columns: wave spans exactly one 64-wide head block
            #pragma unroll
            for (int i = 0; i < MI; i++)
                #pragma unroll
                for (int jp = 0; jp < 2; jp++)
                    #pragma unroll
                    for (int r = 0; r < 4; r++) {
                        int row = m0 + wm + i * 16 + quad * 4 + r;
                        int n = row & 2047;
                        int d1 = jp * 16 + lr;
                        float c1 = cst[n * 64 + d1],      s1 = snt[n * 64 + d1];
                        float c2 = cst[n * 64 + d1 + 32], s2 = snt[n * 64 + d1 + 32];
                        float x1 = acc[i][jp][r], x2 = acc[i][jp + 2][r];
                        Cb[(size_t)row * Nn + n0 + wn + d1]      = f2bf(x1 * c1 - x2 * s1);
                        Cb[(size_t)row * Nn + n0 + wn + d1 + 32] = f2bf(x2 * c2 + x1 * s2);
                    }
        } else {
            // v columns: LDS transpose (reuse freed smem) then coalesced 16B row stores to vt
            #pragma unroll
            for (int i = 0; i < MI; i++)
                #pragma unroll
                for (int j = 0; j < NJ; j++) {
                    u16x4 w;
                    w.x = f2bf(acc[i][j][0]); w.y = f2bf(acc[i][j][1]);
                    w.z = f2bf(acc[i][j][2]); w.w = f2bf(acc[i][j][3]);
                    *(u16x4*)(&smem[(wn + j * 16 + lr) * 132 + wm + i * 16 + quad * 4]) = w;
                }
            __syncthreads();
            int d = tid >> 1, half = tid & 1;
            int gcol = n0 - 2048 + d;
            int hv = gcol >> 6, dl = gcol & 63;
            int bb = m0 >> 11;
            int nloc = (m0 & 2047) + half * 64;
            u16* dst = Vt + ((size_t)((bb * 16 + hv) * 64 + dl)) * 2048 + nloc;
            #pragma unroll
            for (int c = 0; c < 8; c++)
                *(short8*)(dst + c * 8) = *(const short8*)(&smem[d * 132 + half * 64 + c * 8]);
        }
        return;
    }
    #pragma unroll
    for (int i = 0; i < MI; i++)
        #pragma unroll
        for (int j = 0; j < NJ; j++)
            #pragma unroll
            for (int r = 0; r < 4; r++) {
                int row = m0 + wm + i * 16 + quad * 4 + r;
                int col = n0 + wn + j * 16 + lr;
                float v = acc[i][j][r];
                if (MODE == 1) {
                    int b = row >> 11;
                    Cf[(size_t)row * Nn + col] = Xres[(size_t)row * Nn + col] + gate[b * 1024 + col] * v;
                } else {
                    Cb[(size_t)row * Nn + col] = f2bf(v * scale);
                }
            }
}

template <int BM, int BN, int MODE, int WPE>
__global__ __launch_bounds__(256, WPE) void gemm_bt(const u16* __restrict__ A, const u16* __restrict__ Bt,
                                                    u16* __restrict__ Cb, float* __restrict__ Cf,
                                                    u16* __restrict__ Vt,
                                                    const float* __restrict__ Xres, const float* __restrict__ gate,
                                                    const float* __restrict__ cst, const float* __restrict__ snt,
                                                    int Nn, int K) {
    gemm_core<BM, BN, MODE>(A, Bt, Cb, Cf, Vt, Xres, gate, cst, snt, 1.f, Nn, K,
                            blockIdx.y * BM, blockIdx.x * BN);
}

// two independent 1024^3 folds (z selects), 128x64 tiles; q-fold scale = 0.125/ln2
__global__ __launch_bounds__(256, 4) void gemm_fold(const u16* A0, const u16* B0, u16* C0,
                                                    const u16* A1, const u16* B1, u16* C1) {
    const u16* A = blockIdx.z ? A1 : A0;
    const u16* Bt = blockIdx.z ? B1 : B0;
    u16* C = blockIdx.z ? C1 : C0;
    float scale = blockIdx.z ? 1.0f : 0.18033688f;
    gemm_core<128, 64, 0>(A, Bt, C, nullptr, nullptr, nullptr, nullptr, nullptr, nullptr, scale,
                          1024, 1024, blockIdx.y * 128, blockIdx.x * 64);
}

// ---------------- flash attention: BQ=128, BK=64, K-split x2, deferred softmax (exp2 domain) ----------------
__global__ __launch_bounds__(256) void k_attn(const u16* __restrict__ qkv, const u16* __restrict__ vt,
                                              u16* __restrict__ dump, float* __restrict__ paL) {
    __shared__ u16 pool[128 * 72];       // Qs view: stride 64 (staged); Pt view: stride 72 (wave-private)
    __shared__ u16 Ks[2][64][64];
    __shared__ u16 Vs[2][64][64];
    int q0 = blockIdx.x * 128;
    int bh = blockIdx.y; int b = bh >> 4, h = bh & 15;
    int z = blockIdx.z;                  // key half
    int kbase = z * 1024;
    int tid = threadIdx.x;
    int lane = tid & 63, wave = tid >> 6;
    int lr = lane & 15, quad = lane >> 4;
    int srow = tid >> 3, scol = (tid & 7) * 8;
    int sg = (((tid & 7) ^ (srow & 7))) * 8;
    int cc[2] = { ((quad ^ (lr & 7))) * 8, (((4 + quad) ^ (lr & 7))) * 8 };

    const u16* kp = qkv + ((size_t)(b * 2048 + kbase + srow)) * 2048 + 1024 + h * 64 + sg;
    const u16* vp = vt + ((size_t)(bh * 64 + srow)) * 2048 + kbase + sg;

    // Q staging (DMA; drained at first barrier)
    #pragma unroll
    for (int p = 0; p < 4; p++)
        gl_lds16(qkv + ((size_t)(b * 2048 + q0 + srow + 32 * p)) * 2048 + h * 64 + sg,
                 pool + (srow + 32 * p) * 64 + scol);

    short8 krA[2], vrA[2], krB[2], vrB[2];
    krA[0] = *(const short8*)(kp);               krA[1] = *(const short8*)(kp + (size_t)32 * 2048);
    vrA[0] = *(const short8*)(vp);               vrA[1] = *(const short8*)(vp + (size_t)32 * 2048);
    __syncthreads();                             // Q (and t0 regs) ready
    short8 qf[2][2];
    #pragma unroll
    for (int rt = 0; rt < 2; rt++)
        #pragma unroll
        for (int ks = 0; ks < 2; ks++)
            qf[rt][ks] = *(const short8*)(pool + (wave * 32 + rt * 16 + lr) * 64 + cc[ks]);
    // t0 -> LDS[0]; t1 -> regs B
    *(short8*)(&Ks[0][srow][scol])      = krA[0];
    *(short8*)(&Ks[0][srow + 32][scol]) = krA[1];
    *(short8*)(&Vs[0][srow][scol])      = vrA[0];
    *(short8*)(&Vs[0][srow + 32][scol]) = vrA[1];
    krB[0] = *(const short8*)(kp + (size_t)64 * 2048);  krB[1] = *(const short8*)(kp + (size_t)96 * 2048);
    vrB[0] = *(const short8*)(vp + 64);                 vrB[1] = *(const short8*)(vp + 64 + (size_t)32 * 2048);
    __syncthreads();

    float l_part[2] = {0.f, 0.f};
    f32x4 oacc[2][4];
    #pragma unroll
    for (int rt = 0; rt < 2; rt++)
        #pragma unroll
        for (int dt = 0; dt < 4; dt++) oacc[rt][dt] = f32x4{0.f, 0.f, 0.f, 0.f};

    auto body = [&](int it, int cur, short8 (&krF)[2], short8 (&vrF)[2],
                    short8 (&krH)[2], short8 (&vrH)[2]) {
        if (it < 14) {   // prefetch t(it+2) into the freed slot
            const u16* kq = kp + (size_t)(it + 2) * 64 * 2048;
            const u16* vq = vp + (it + 2) * 64;
            krF[0] = *(const short8*)(kq);  krF[1] = *(const short8*)(kq + (size_t)32 * 2048);
            vrF[0] = *(const short8*)(vq);  vrF[1] = *(const short8*)(vq + (size_t)32 * 2048);
        }
        // S^T[key][qrow] = mfma(A=K, B=Q)
        f32x4 st[2][4];
        #pragma unroll
        for (int rt = 0; rt < 2; rt++)
            #pragma unroll
            for (int ct = 0; ct < 4; ct++) st[rt][ct] = f32x4{0.f, 0.f, 0.f, 0.f};
        #pragma unroll
        for (int ks = 0; ks < 2; ks++) {
            short8 kf[4];
            #pragma unroll
            for (int ct = 0; ct < 4; ct++)
                kf[ct] = *(const short8*)(&Ks[cur][ct * 16 + lr][cc[ks]]);
            #pragma unroll
            for (int rt = 0; rt < 2; rt++)
                #pragma unroll
                for (int ct = 0; ct < 4; ct++)
                    st[rt][ct] = __builtin_amdgcn_mfma_f32_16x16x32_bf16(kf[ct], qf[rt][ks], st[rt][ct], 0, 0, 0);
        }
        // p = exp2(s); per-lane row sums (qrow = lr); packed b64 P-store, Pt[qrow][key] (wave-private)
        #pragma unroll
        for (int rt = 0; rt < 2; rt++)
            #pragma unroll
            for (int ct = 0; ct < 4; ct++) {
                float p0 = fexp2(st[rt][ct][0]);
                float p1 = fexp2(st[rt][ct][1]);
                float p2 = fexp2(st[rt][ct][2]);
                float p3 = fexp2(st[rt][ct][3]);
                l_part[rt] += (p0 + p1) + (p2 + p3);
                uint2v w; w.x = pk2(p0, p1); w.y = pk2(p2, p3);
                *(uint2v*)(pool + (wave * 32 + rt * 16 + lr) * 72 + ct * 16 + quad * 4) = w;
            }
        // O += P V
        #pragma unroll
        for (int ks = 0; ks < 2; ks++) {
            short8 pf[2], vf[4];
            #pragma unroll
            for (int rt = 0; rt < 2; rt++)
                pf[rt] = *(const short8*)(pool + (wave * 32 + rt * 16 + lr) * 72 + ks * 32 + quad * 8);
            #pragma unroll
            for (int dt = 0; dt < 4; dt++)
                vf[dt] = *(const short8*)(&Vs[cur][dt * 16 + lr][cc[ks]]);
            #pragma unroll
            for (int rt = 0; rt < 2; rt++)
                #pragma unroll
                for (int dt = 0; dt < 4; dt++)
                    oacc[rt][dt] = __builtin_amdgcn_mfma_f32_16x16x32_bf16(pf[rt], vf[dt], oacc[rt][dt], 0, 0, 0);
        }
        // hand tile t(it+1) to the next LDS buffer (waits this wave's vmcnt only)
        if (it < 15) {
            int nxt = cur ^ 1;
            *(short8*)(&Ks[nxt][srow][scol])      = krH[0];
            *(short8*)(&Ks[nxt][srow + 32][scol]) = krH[1];
            *(short8*)(&Vs[nxt][srow][scol])      = vrH[0];
            *(short8*)(&Vs[nxt][srow + 32][scol]) = vrH[1];
        }
        __syncthreads();
    };

    #pragma unroll 1
    for (int it2 = 0; it2 < 8; ++it2) {
        body(2 * it2,     0, krA, vrA, krB, vrB);
        body(2 * it2 + 1, 1, krB, vrB, krA, vrA);
    }

    // l reduction across quads; store raw sums
    #pragma unroll
    for (int rt = 0; rt < 2; rt++) {
        float l = l_part[rt];
        l += __shfl_xor(l, 16, 64);
        l += __shfl_xor(l, 32, 64);
        if (quad == 0)
            paL[(size_t)z * 65536 + bh * 2048 + q0 + wave * 32 + rt * 16 + lr] = l;
    }
    // unnormalized bf16 O partials, thread-linear dump (coalesced 64B/thread)
    u16* dp = dump + (size_t)z * 4194304 + ((size_t)(bh * 16 + blockIdx.x) * 256 + tid) * 32;
    #pragma unroll
    for (int rt = 0; rt < 2; rt++)
        #pragma unroll
        for (int dt = 0; dt < 4; dt++) {
            u16x4 w;
            w.x = f2bf(oacc[rt][dt][0]); w.y = f2bf(oacc[rt][dt][1]);
            w.z = f2bf(oacc[rt][dt][2]); w.w = f2bf(oacc[rt][dt][3]);
            *(u16x4*)(dp + rt * 16 + dt * 4) = w;
        }
}

// ---------------- combine K-split partials: aob = (O0+O1)/(l0+l1); mirrors k_attn's dump layout ----------------
__global__ __launch_bounds__(256) void k_comb(const u16* __restrict__ dump, const float* __restrict__ paL,
                                              u16* __restrict__ aob) {
    int bx = blockIdx.x, bh = blockIdx.y;
    int b = bh >> 4, h = bh & 15;
    int tid = threadIdx.x;
    int lane = tid & 63, wave = tid >> 6;
    int lr = lane & 15, quad = lane >> 4;
    int q0 = bx * 128;
    const u16* d0 = dump + ((size_t)(bh * 16 + bx) * 256 + tid) * 32;
    const u16* d1 = d0 + 4194304;
    #pragma unroll
    for (int rt = 0; rt < 2; rt++) {
        float inv[4];
        #pragma unroll
        for (int r = 0; r < 4; r++) {
            int row = q0 + wave * 32 + rt * 16 + quad * 4 + r;
            float l0 = paL[bh * 2048 + row];
            float l1 = paL[65536 + bh * 2048 + row];
            inv[r] = 1.f / (l0 + l1);
        }
        #pragma unroll
        for (int dt = 0; dt < 4; dt++) {
            u16x4 w0 = *(const u16x4*)(d0 + rt * 16 + dt * 4);
            u16x4 w1 = *(const u16x4*)(d1 + rt * 16 + dt * 4);
            #pragma unroll
            for (int r = 0; r < 4; r++) {
                int row = q0 + wave * 32 + rt * 16 + quad * 4 + r;
                float o = (bf2f(((const u16*)&w0)[r]) + bf2f(((const u16*)&w1)[r])) * inv[r];
                aob[((size_t)(b * 2048 + row)) * 1024 + h * 64 + dt * 16 + lr] = f2bf(o);
            }
        }
    }
}

// ---------------- launch ----------------
extern "C" void kernel_launch(void* const* d_in, const int* in_sizes, int n_in,
                              void* d_out, int out_size, void* d_ws, size_t ws_size,
                              hipStream_t stream) {
    const float* x     = (const float*)d_in[0];
    const float* emb   = (const float*)d_in[1];
    const float* gate  = (const float*)d_in[2];
    // d_in[3] crossattn_emb: unused by the reference
    const float* rope  = (const float*)d_in[4];
    const float* Wq1   = (const float*)d_in[5];
    const float* Wq2   = (const float*)d_in[6];
    const float* Wk1   = (const float*)d_in[7];
    const float* Wk2   = (const float*)d_in[8];
    const float* Wv    = (const float*)d_in[9];
    const float* Wo    = (const float*)d_in[10];
    const float* Wada1 = (const float*)d_in[11];
    const float* Wada2 = (const float*)d_in[12];
    const float* bada2 = (const float*)d_in[13];
    float* out = (float*)d_out;

    char* ws = (char*)d_ws;
    size_t off = 0;
    auto alloc = [&](size_t bytes) { void* p = ws + off; off += (bytes + 255) & ~(size_t)255; return p; };
    float* t_ada = (float*)alloc(2048 * 4);
    float* ada   = (float*)alloc(4096 * 4);
    float* cst   = (float*)alloc((size_t)131072 * 4);
    float* snt   = (float*)alloc((size_t)131072 * 4);
    u16* xn    = (u16*)alloc((size_t)4096 * 1024 * 2);
    u16* Wq1b  = (u16*)alloc((size_t)1024 * 1024 * 2);
    u16* Wk1b  = (u16*)alloc((size_t)1024 * 1024 * 2);
    u16* Wq2t  = (u16*)alloc((size_t)1024 * 1024 * 2);
    u16* Wk2t  = (u16*)alloc((size_t)1024 * 1024 * 2);
    u16* Wot   = (u16*)alloc((size_t)1024 * 1024 * 2);
    u16* WqkvT = (u16*)alloc((size_t)3072 * 1024 * 2);   // rows: WqeT | WkeT | WvT
    u16* qkvb  = (u16*)alloc((size_t)4096 * 2048 * 2);   // q|k (roped), row stride 2048
    u16* vtb   = (u16*)alloc((size_t)4096 * 1024 * 2);   // vt[bh][d][n]
    u16* aob   = (u16*)alloc((size_t)4096 * 1024 * 2);
    u16* dumpO = (u16*)alloc((size_t)2 * 4194304 * 2);   // bf16 O partials, thread-linear
    float* paL = (float*)alloc((size_t)2 * 65536 * 4);
    (void)ws_size; (void)in_sizes; (void)n_in; (void)out_size;

    // zero accumulation targets for atomic K-split
    hipMemsetAsync(t_ada, 0, 2048 * 4, stream);
    hipMemsetAsync(ada, 0, 4096 * 4, stream);

    // adaLN stage 1 (widened, atomics)
    k_ada1<<<dim3(16, 2, 8), 256, 0, stream>>>(emb, Wada1, t_ada);

    // prep: weight conversions + ada2 (atomics) + rope tables
    k_prep<<<dim3(16, 16, 8), 256, 0, stream>>>(Wq2, Wq2t, Wk2, Wk2t,
                                                Wv, WqkvT + (size_t)2048 * 1024, Wo, Wot,
                                                Wq1, Wq1b, Wk1, Wk1b,
                                                t_ada, Wada2, ada, rope, cst, snt);

    // LayerNorm + modulate (ada2 bias folded in)
    k_ln<<<4096, 256, 0, stream>>>(x, ada, bada2, xn);

    // fold stacked projections (WqeT scale = 0.125/ln2 for exp2-domain softmax), 128x64 tiles
    gemm_fold<<<dim3(16, 8, 2), 256, 0, stream>>>(Wq2t, Wq1b, WqkvT,
                                                  Wk2t, Wk1b, WqkvT + (size_t)1024 * 1024);

    // fused QKV projection + rope epilogue + LDS-transposed V store (BK=32 dbuf, 3 blocks/CU)
    gemm_bt<128, 128, 2, 3><<<dim3(24, 32), 256, 0, stream>>>(xn, WqkvT, qkvb, nullptr, vtb,
                                                              nullptr, nullptr, cst, snt, 2048, 1024);

    // flash attention (K-split x2) + combine
    k_attn<<<dim3(16, 32, 2), 256, 0, stream>>>(qkvb, vtb, dumpO, paL);
    k_comb<<<dim3(16, 32), 256, 0, stream>>>(dumpO, paL, aob);

    // final projection + gated residual (fp32 out, BK=32 dbuf)
    gemm_bt<128, 64, 1, 4><<<dim3(16, 32), 256, 0, stream>>>(aob, Wot, nullptr, out, nullptr, x, gate,
                                                             nullptr, nullptr, 1024, 1024);
}